// Round 12
// baseline (333.826 us; speedup 1.0000x reference)
//
#include <hip/hip_runtime.h>
#include <math.h>

#define NN 100000
#define NE 1600000
#define NG 2048
#define NBUK 391     // ceil(NN/256) dst-buckets, bucket = dst >> 8
#define SLOT 6144    // per-bucket capacity: mean 4096 + 32 sigma
#define CHUNK 8192   // edges per bin block
#define FILLB 391    // fill-path blocks in fused kernel
#define GEMMB 832    // gemm blocks (3328 waves, ~1.9 m-tiles/wave)

typedef __attribute__((ext_vector_type(8))) short short8;
typedef __attribute__((ext_vector_type(8))) __bf16 bf16x8;
typedef __attribute__((ext_vector_type(4))) float f32x4;
typedef __attribute__((ext_vector_type(2))) float f32x2;
typedef __attribute__((ext_vector_type(4))) unsigned int uint4_;

__device__ __forceinline__ unsigned short f2bf(float f) {       // RNE, finite inputs
    unsigned int u = __float_as_uint(f);
    return (unsigned short)((u + 0x7FFFu + ((u >> 16) & 1u)) >> 16);
}
__device__ __forceinline__ float bf2f(unsigned short s) {
    return __uint_as_float(((unsigned int)s) << 16);
}
__device__ __forceinline__ unsigned char f2fp8(float v) {       // HW cvt, e4m3fn
    int p = __builtin_amdgcn_cvt_pk_fp8_f32(v, v, 0, false);
    return (unsigned char)(p & 0xFF);
}

// ---------------- setup: w2bf (transposed) + grange + gcnt zero + loss-slot zero ----------------
__global__ __launch_bounds__(256) void setup_kernel(const float* __restrict__ W1,
                                                    const float* __restrict__ W2,
                                                    const float* __restrict__ W3,
                                                    unsigned short* __restrict__ Wb1t,
                                                    unsigned short* __restrict__ Wb2t,
                                                    unsigned short* __restrict__ Wb3t,
                                                    const int* __restrict__ batch,
                                                    int* __restrict__ gstart,
                                                    int* __restrict__ gcnt,
                                                    float* __restrict__ out) {
    const int bid = blockIdx.x, t = threadIdx.x;
    if (bid < 104) {                                  // weight cvt+transpose (26624 elems)
        int i = bid * 256 + t;
        if (i < 16384) {                              // W1: 128x128
            int k = i >> 7, c = i & 127;
            Wb1t[c * 128 + k] = f2bf(W1[i]);
        } else if (i < 24576) {                       // W2: 128x64
            int j = i - 16384; int k = j >> 6, c = j & 63;
            Wb2t[c * 128 + k] = f2bf(W2[j]);
        } else if (i < 26624) {                       // W3: 64x32
            int j = i - 24576; int k = j >> 5, c = j & 31;
            Wb3t[c * 64 + k] = f2bf(W3[j]);
        }
    } else if (bid < 113) {                           // grange (batch sorted)
        int g = (bid - 104) * 256 + t;
        if (g > NG) return;
        if (g == NG) { gstart[g] = NN; return; }
        int lo = 0, hi = NN;
        while (lo < hi) { int mid = (lo + hi) >> 1; if (batch[mid] < g) lo = mid + 1; else hi = mid; }
        gstart[g] = lo;
    } else {                                          // zero gcnt (512 ints) + loss accumulator
        gcnt[t] = 0; gcnt[t + 256] = 0;
        if (t == 0) out[NG] = 0.0f;
    }
}

// ---------------- pass 1: bin edges by dst>>8, bucket-sorted block appends ----------------
__global__ __launch_bounds__(256) void bin_kernel(const int* __restrict__ src,
                                                  const int* __restrict__ dst,
                                                  int* __restrict__ gcnt,
                                                  int* __restrict__ bucket_data, int E) {
    __shared__ int cnt[512];                 // padded scan array
    __shared__ int offs[NBUK];
    __shared__ int cnt2[NBUK];
    __shared__ int gb[NBUK];
    __shared__ int packB[CHUNK];
    __shared__ unsigned short bktB[CHUNK];
    const int t = threadIdx.x;
    const int E0 = blockIdx.x * CHUNK;
    const int valid = min(CHUNK, E - E0);
    cnt[t] = 0; cnt[t + 256] = 0;
    for (int i = t; i < NBUK; i += 256) cnt2[i] = 0;
    __syncthreads();
    // A: count buckets
    for (int i = t; i < valid; i += 256)
        atomicAdd(&cnt[dst[E0 + i] >> 8], 1);
    __syncthreads();
    int o0 = cnt[t], o1 = cnt[t + 256];
    // B: inclusive Hillis-Steele scan over 512 (2 elems/thread)
    for (int off = 1; off < 512; off <<= 1) {
        int a0 = (t >= off) ? cnt[t - off] : 0;
        int a1 = (t + 256 >= off) ? cnt[t + 256 - off] : 0;
        __syncthreads();
        cnt[t] += a0; cnt[t + 256] += a1;
        __syncthreads();
    }
    if (t < NBUK)       { offs[t] = cnt[t] - o0;             gb[t] = o0 ? atomicAdd(&gcnt[t], o0) : 0; }
    if (t + 256 < NBUK) { offs[t + 256] = cnt[t + 256] - o1; gb[t + 256] = o1 ? atomicAdd(&gcnt[t + 256], o1) : 0; }
    __syncthreads();
    // C: re-read edges, place bucket-sorted into LDS
    for (int i = t; i < valid; i += 256) {
        int s = src[E0 + i], d = dst[E0 + i];
        int b = d >> 8;
        int pos = offs[b] + atomicAdd(&cnt2[b], 1);
        packB[pos] = (s << 8) | (d & 255);
        bktB[pos] = (unsigned short)b;
    }
    __syncthreads();
    // D: contiguous-per-bucket append to global streams
    for (int i = t; i < valid; i += 256) {
        int b = bktB[i];
        int idx = gb[b] + (i - offs[b]);
        if (idx < SLOT) bucket_data[b * SLOT + idx] = packB[i];
    }
}

// ---------------- pass 2a: per-bucket counts -> dinv + rowptr (base scanned inline) ----------------
__global__ __launch_bounds__(256) void csr2a_kernel(const int* __restrict__ gcnt,
                                                    const int* __restrict__ bucket_data,
                                                    float* __restrict__ dinv,
                                                    int* __restrict__ rowptr) {
    __shared__ int bs[512];
    __shared__ int counts[256];
    __shared__ int base_sh;
    const int t = threadIdx.x;
    const int b = blockIdx.x;
    // inline exclusive scan of min(gcnt,SLOT) over all buckets (redundant per block)
    bs[t] = (t < NBUK) ? min(gcnt[t], SLOT) : 0;
    bs[t + 256] = (t + 256 < NBUK) ? min(gcnt[t + 256], SLOT) : 0;
    counts[t] = 0;
    __syncthreads();
    for (int off = 1; off < 512; off <<= 1) {
        int a0 = (t >= off) ? bs[t - off] : 0;
        int a1 = (t + 256 >= off) ? bs[t + 256 - off] : 0;
        __syncthreads();
        bs[t] += a0; bs[t + 256] += a1;
        __syncthreads();
    }
    if (t == 0) base_sh = bs[b] - min(gcnt[b], SLOT);   // exclusive base
    __syncthreads();
    const int cb = min(gcnt[b], SLOT);
    const int* bd = bucket_data + b * SLOT;
    for (int i = t; i < cb; i += 256) atomicAdd(&counts[bd[i] & 255], 1);
    __syncthreads();
    int c = counts[t];
    for (int off = 1; off < 256; off <<= 1) {
        int a = (t >= off) ? counts[t - off] : 0;
        __syncthreads();
        counts[t] += a;
        __syncthreads();
    }
    int excl = counts[t] - c;
    int node = b * 256 + t;
    if (node < NN) {
        dinv[node] = rsqrtf((float)c + 1.0f);
        rowptr[node] = base_sh + excl;
    }
    if (b == NBUK - 1 && t == 0) rowptr[NN] = NE;
}

// ---------------- MFMA GEMM body ----------------
// One wave per 16-row m-tile computing ALL FOUT cols; grid-stride with register
// double-buffer: next A-tile loads issue BEFORE current tile's MFMA block.
// OUT_FP8: hs written CHUNK-MAJOR fp8 [col/32][n][col%32] (32-col slice = 3.2 MB -> one XCD L2).
// Layouts [m89-verified]: A: m=lane&15, k=quad*8+j ; B: n=lane&15, k=quad*8+j ;
//                         C/D: col=lane&15, row=quad*4+reg.
template<int FIN, int FOUT, bool RELU_IN, bool A_BF16, bool OUT_FP8>
__device__ __forceinline__ void gemm_body(const void* __restrict__ in_,
                                          const unsigned short* __restrict__ Wbt,
                                          const float* __restrict__ dinv,
                                          void* __restrict__ out,
                                          int N, int nwaves, int wid, int lane) {
    constexpr int NT = FOUT / 16;
    constexpr int KS = FIN / 32;
    const int m16  = lane & 15;
    const int quad = lane >> 4;
    const int koff = quad * 8;

    short8 bfrag[NT][KS];
#pragma unroll
    for (int nt = 0; nt < NT; ++nt) {
        const unsigned short* wcol = Wbt + (size_t)(m16 + nt * 16) * FIN + koff;
#pragma unroll
        for (int ks = 0; ks < KS; ++ks)
            bfrag[nt][ks] = *(const short8*)(wcol + ks * 32);
    }

    const int MT = N / 16;                 // N == 100000 -> exact
    int mt = wid;
    if (mt >= MT) return;

    short8 curB[KS], nxtB[KS];
    f32x4  curF[KS][2], nxtF[KS][2];

    auto load_raw = [&](int m, short8* rb, f32x4 (*rf)[2]) {
        const int row = m * 16 + m16;
        if (A_BF16) {
            const unsigned short* A = (const unsigned short*)in_ + (size_t)row * FIN + koff;
#pragma unroll
            for (int ks = 0; ks < KS; ++ks) rb[ks] = *(const short8*)(A + ks * 32);
        } else {
            const float* A = (const float*)in_ + (size_t)row * FIN + koff;
#pragma unroll
            for (int ks = 0; ks < KS; ++ks) {
                rf[ks][0] = *(const f32x4*)(A + ks * 32);
                rf[ks][1] = *(const f32x4*)(A + ks * 32 + 4);
            }
        }
    };

    load_raw(mt, curB, curF);
    while (true) {
        const int mtn = mt + nwaves;
        const bool have_next = (mtn < MT);
        if (have_next) load_raw(mtn, nxtB, nxtF);   // in flight across the MFMAs below

        short8 afrag[KS];
        if (A_BF16) {
#pragma unroll
            for (int ks = 0; ks < KS; ++ks) {
                short8 a = curB[ks];
                if (RELU_IN) {
#pragma unroll
                    for (int j = 0; j < 8; ++j)
                        a[j] = (short)(((unsigned short)a[j] & 0x8000u) ? 0 : (unsigned short)a[j]);
                }
                afrag[ks] = a;
            }
        } else {
#pragma unroll
            for (int ks = 0; ks < KS; ++ks) {
#pragma unroll
                for (int j = 0; j < 4; ++j) {
                    float a0 = curF[ks][0][j], a1 = curF[ks][1][j];
                    if (RELU_IN) { a0 = fmaxf(a0, 0.f); a1 = fmaxf(a1, 0.f); }
                    afrag[ks][j]     = (short)f2bf(a0);
                    afrag[ks][j + 4] = (short)f2bf(a1);
                }
            }
        }

        f32x4 acc[NT];
#pragma unroll
        for (int nt = 0; nt < NT; ++nt) acc[nt] = (f32x4){0.f, 0.f, 0.f, 0.f};
#pragma unroll
        for (int nt = 0; nt < NT; ++nt)
#pragma unroll
            for (int ks = 0; ks < KS; ++ks)
                acc[nt] = __builtin_amdgcn_mfma_f32_16x16x32_bf16(
                    __builtin_bit_cast(bf16x8, afrag[ks]),
                    __builtin_bit_cast(bf16x8, bfrag[nt][ks]), acc[nt], 0, 0, 0);

        float dv[4];
#pragma unroll
        for (int r = 0; r < 4; ++r) dv[r] = dinv[mt * 16 + quad * 4 + r];
#pragma unroll
        for (int nt = 0; nt < NT; ++nt) {
#pragma unroll
            for (int r = 0; r < 4; ++r) {
                int orow = mt * 16 + quad * 4 + r;
                float v = acc[nt][r] * dv[r];
                if (OUT_FP8) {
                    int chunk = nt >> 1;
                    int incol = m16 + (nt & 1) * 16;
                    ((unsigned char*)out)[(size_t)chunk * N * 32 + (size_t)orow * 32 + incol] = f2fp8(v);
                } else {
                    ((unsigned short*)out)[(size_t)orow * FOUT + (m16 + nt * 16)] = f2bf(v);
                }
            }
        }

        if (!have_next) break;
#pragma unroll
        for (int ks = 0; ks < KS; ++ks) {
            curB[ks] = nxtB[ks];
            curF[ks][0] = nxtF[ks][0];
            curF[ks][1] = nxtF[ks][1];
        }
        mt = mtn;
    }
}

// ---------------- fused: CSR fine-scatter (blocks 0..390) || gemm1 (rest) ----------------
__global__ __launch_bounds__(256, 2) void fill_gemm1_kernel(const int* __restrict__ gcnt,
                                                            const int* __restrict__ bucket_data,
                                                            const int* __restrict__ rowptr,
                                                            int* __restrict__ csr_src,
                                                            const float* __restrict__ x,
                                                            const unsigned short* __restrict__ Wb1t,
                                                            const float* __restrict__ dinv,
                                                            unsigned char* __restrict__ hs) {
    __shared__ int offs[256];
    __shared__ int cnt2[256];
    const int t = threadIdx.x;
    if (blockIdx.x < FILLB) {
        const int b = blockIdx.x;
        const int cb = min(gcnt[b], SLOT);
        const int* bd = bucket_data + b * SLOT;
        int node = b * 256 + t;
        offs[t] = (node < NN) ? rowptr[node] : 0;
        cnt2[t] = 0;
        __syncthreads();
        for (int i = t; i < cb; i += 256) {
            int p = bd[i];
            int local = p & 255;
            int pos = atomicAdd(&cnt2[local], 1);
            csr_src[offs[local] + pos] = p >> 8;   // p>=0, arith shift ok
        }
    } else {
        const int wid = ((blockIdx.x - FILLB) * 256 + t) >> 6;
        gemm_body<128, 128, false, false, true>(x, Wb1t, dinv, hs, NN, GEMMB * 4, wid, t & 63);
    }
}

// ---------------- standalone GEMMs (layers 2,3) ----------------
template<int FIN, int FOUT, bool RELU_IN, bool A_BF16, bool OUT_FP8>
__global__ __launch_bounds__(256, 2) void mfma_gemm(const void* __restrict__ in_,
                                                    const unsigned short* __restrict__ Wbt,
                                                    const float* __restrict__ dinv,
                                                    void* __restrict__ out,
                                                    int N, int nwaves) {
    const int wid = (blockIdx.x * 256 + threadIdx.x) >> 6;
    gemm_body<FIN, FOUT, RELU_IN, A_BF16, OUT_FP8>(in_, Wbt, dinv, out, N, nwaves, wid, threadIdx.x & 63);
}

// ---------------- XCD-affine chunked fp8 gather-aggregate ----------------
// hs chunk-major [F/32][N][32] fp8; chunk slice = 3.2 MB (fits one XCD 4MB L2).
// chunk = blockIdx % NCH -> round-robin XCD dispatch pins 1-2 chunks per XCD.
// Lane: 16 cols (16 B load), 2 lanes/node, 128 nodes/block; out bf16 row-major.
template<int F>
__global__ __launch_bounds__(256) void agg8c_kernel(const int* __restrict__ rowptr,
                                                    const int* __restrict__ csr_src,
                                                    const unsigned char* __restrict__ hs,
                                                    const float* __restrict__ dinv,
                                                    const float* __restrict__ b,
                                                    unsigned short* __restrict__ aggout, int N) {
    constexpr int NCH = F / 32;
    const int chunk = blockIdx.x % NCH;
    const int nb    = blockIdx.x / NCH;
    const int n     = nb * 128 + (threadIdx.x >> 1);
    const int half  = threadIdx.x & 1;               // 16 cols each
    if (n >= N) return;
    const uint4_* hp = (const uint4_*)(hs + (size_t)chunk * N * 32);   // row = 2 uint4
    int row = rowptr[n], end = rowptr[n + 1];
    float acc[16];
    {
        uint4_ u = hp[(size_t)n * 2 + half];          // self term
#pragma unroll
        for (int w = 0; w < 4; ++w) {
            f32x2 lo = __builtin_amdgcn_cvt_pk_f32_fp8(u[w], false);
            f32x2 hi = __builtin_amdgcn_cvt_pk_f32_fp8(u[w], true);
            acc[w * 4 + 0] = lo[0]; acc[w * 4 + 1] = lo[1];
            acc[w * 4 + 2] = hi[0]; acc[w * 4 + 3] = hi[1];
        }
    }
    int j = row;
    for (; j + 4 <= end; j += 4) {
        int s0 = csr_src[j], s1 = csr_src[j + 1], s2 = csr_src[j + 2], s3 = csr_src[j + 3];
        uint4_ u0 = hp[(size_t)s0 * 2 + half];
        uint4_ u1 = hp[(size_t)s1 * 2 + half];
        uint4_ u2 = hp[(size_t)s2 * 2 + half];
        uint4_ u3 = hp[(size_t)s3 * 2 + half];
#pragma unroll
        for (int w = 0; w < 4; ++w) {
            f32x2 a0 = __builtin_amdgcn_cvt_pk_f32_fp8(u0[w], false);
            f32x2 b0 = __builtin_amdgcn_cvt_pk_f32_fp8(u0[w], true);
            f32x2 a1 = __builtin_amdgcn_cvt_pk_f32_fp8(u1[w], false);
            f32x2 b1 = __builtin_amdgcn_cvt_pk_f32_fp8(u1[w], true);
            f32x2 a2 = __builtin_amdgcn_cvt_pk_f32_fp8(u2[w], false);
            f32x2 b2 = __builtin_amdgcn_cvt_pk_f32_fp8(u2[w], true);
            f32x2 a3 = __builtin_amdgcn_cvt_pk_f32_fp8(u3[w], false);
            f32x2 b3 = __builtin_amdgcn_cvt_pk_f32_fp8(u3[w], true);
            acc[w * 4 + 0] += (a0[0] + a1[0]) + (a2[0] + a3[0]);
            acc[w * 4 + 1] += (a0[1] + a1[1]) + (a2[1] + a3[1]);
            acc[w * 4 + 2] += (b0[0] + b1[0]) + (b2[0] + b3[0]);
            acc[w * 4 + 3] += (b0[1] + b1[1]) + (b2[1] + b3[1]);
        }
    }
    for (; j < end; ++j) {
        uint4_ u = hp[(size_t)csr_src[j] * 2 + half];
#pragma unroll
        for (int w = 0; w < 4; ++w) {
            f32x2 lo = __builtin_amdgcn_cvt_pk_f32_fp8(u[w], false);
            f32x2 hi = __builtin_amdgcn_cvt_pk_f32_fp8(u[w], true);
            acc[w * 4 + 0] += lo[0]; acc[w * 4 + 1] += lo[1];
            acc[w * 4 + 2] += hi[0]; acc[w * 4 + 3] += hi[1];
        }
    }
    float c = dinv[n];
    const int cb = chunk * 32 + half * 16;
    short8 o0, o1;
#pragma unroll
    for (int k = 0; k < 8; ++k) {
        o0[k] = (short)f2bf(fmaf(acc[k], c, b[cb + k]));
        o1[k] = (short)f2bf(fmaf(acc[k + 8], c, b[cb + 8 + k]));
    }
    unsigned short* op = aggout + (size_t)n * F + cb;
    *(short8*)op = o0;
    *(short8*)(op + 8) = o1;
}

// ---------------- fused layer-3 tail: gather-agg + mean-pool + logit + BCE ----------------
// One block per graph (batch sorted -> nodes [gstart[g], gstart[g+1]) contiguous).
// hs3 is bf16 row-major [N][32]. out[g]=sigmoid(logit); out[NG] += loss/NG (atomic).
__global__ __launch_bounds__(256) void aggpool_kernel(const int* __restrict__ rowptr,
                                                      const int* __restrict__ csr_src,
                                                      const unsigned short* __restrict__ hs,
                                                      const float* __restrict__ dinv,
                                                      const float* __restrict__ b,
                                                      const int* __restrict__ gstart,
                                                      const float* __restrict__ Wl,
                                                      const float* __restrict__ bl,
                                                      const int* __restrict__ targets,
                                                      float* __restrict__ out) {
    constexpr int F = 32;
    __shared__ float sm[64][33];                      // 64 node-slots x 32 cols (+pad)
    const int g = blockIdx.x;
    const int s = gstart[g], e = gstart[g + 1];
    const int slot = threadIdx.x >> 2;                // 0..63
    const int c8 = (threadIdx.x & 3) * 8;
    float accp[8];
#pragma unroll
    for (int k = 0; k < 8; ++k) accp[k] = 0.f;
    for (int n = s + slot; n < e; n += 64) {
        int row = rowptr[n], end = rowptr[n + 1];
        float acc[8];
        {
            short8 h = *(const short8*)(hs + (size_t)n * F + c8);   // self term
#pragma unroll
            for (int k = 0; k < 8; ++k) acc[k] = bf2f((unsigned short)h[k]);
        }
        int j = row;
        for (; j + 4 <= end; j += 4) {
            int s0 = csr_src[j], s1 = csr_src[j + 1], s2 = csr_src[j + 2], s3 = csr_src[j + 3];
            short8 h0 = *(const short8*)(hs + (size_t)s0 * F + c8);
            short8 h1 = *(const short8*)(hs + (size_t)s1 * F + c8);
            short8 h2 = *(const short8*)(hs + (size_t)s2 * F + c8);
            short8 h3 = *(const short8*)(hs + (size_t)s3 * F + c8);
#pragma unroll
            for (int k = 0; k < 8; ++k)
                acc[k] += (bf2f((unsigned short)h0[k]) + bf2f((unsigned short)h1[k])) +
                          (bf2f((unsigned short)h2[k]) + bf2f((unsigned short)h3[k]));
        }
        for (; j < end; ++j) {
            short8 h = *(const short8*)(hs + (size_t)csr_src[j] * F + c8);
#pragma unroll
            for (int k = 0; k < 8; ++k) acc[k] += bf2f((unsigned short)h[k]);
        }
        float c = dinv[n];
#pragma unroll
        for (int k = 0; k < 8; ++k) accp[k] += fmaf(acc[k], c, b[c8 + k]);
    }
#pragma unroll
    for (int k = 0; k < 8; ++k) sm[slot][c8 + k] = accp[k];
    __syncthreads();
    // reduce 64 slots -> 8 -> 1
    const int col = threadIdx.x & 31, part = threadIdx.x >> 5;
    float v = 0.f;
    for (int ss = part * 8; ss < part * 8 + 8; ++ss) v += sm[ss][col];
    __syncthreads();
    sm[part][col] = v;
    __syncthreads();
    if (threadIdx.x < 32) {
        float tot = 0.f;
        for (int p = 0; p < 8; ++p) tot += sm[p][threadIdx.x];
        float cnt = fmaxf((float)(e - s), 1.0f);
        sm[8][threadIdx.x] = (tot / cnt) * Wl[threadIdx.x];
    }
    __syncthreads();
    if (threadIdx.x == 0) {
        float logit = bl[0];
        for (int k = 0; k < 32; ++k) logit += sm[8][k];
        out[g] = 1.0f / (1.0f + expf(-logit));
        float y = (float)targets[g];
        float l = fmaxf(logit, 0.0f) - logit * y + log1pf(expf(-fabsf(logit)));
        atomicAdd(out + NG, l / (float)NG);
    }
}

extern "C" void kernel_launch(void* const* d_in, const int* in_sizes, int n_in,
                              void* d_out, int out_size, void* d_ws, size_t ws_size,
                              hipStream_t stream) {
    const float* x       = (const float*)d_in[0];
    const int*   ei      = (const int*)d_in[1];
    const int*   batch   = (const int*)d_in[2];
    const int*   targets = (const int*)d_in[3];
    const float* W1 = (const float*)d_in[4];
    const float* b1 = (const float*)d_in[5];
    const float* W2 = (const float*)d_in[6];
    const float* b2 = (const float*)d_in[7];
    const float* W3 = (const float*)d_in[8];
    const float* b3 = (const float*)d_in[9];
    const float* Wl = (const float*)d_in[10];
    const float* bl = (const float*)d_in[11];
    float* out = (float*)d_out;
    char*  ws  = (char*)d_ws;

    const int* src = ei;
    const int* dst = ei + NE;

    // workspace layout (byte offsets, 512B aligned) — total ~68.3 MB
    float*          dinv    = (float*)(ws);                    //    400,384 B
    int*            rowptr  = (int*)(ws + 400384);             //    400,384 B (NN+1)
    int*            csr_src = (int*)(ws + 800768);             //  6,400,512 B
    unsigned short* Wb1t    = (unsigned short*)(ws + 7201280); //     32,768 B (transposed)
    unsigned short* Wb2t    = (unsigned short*)(ws + 7234048); //     16,384 B (transposed)
    unsigned short* Wb3t    = (unsigned short*)(ws + 7250432); //      4,096 B (transposed)
    int*            gstart  = (int*)(ws + 7254528);            //      8,704 B (NG+1)
    unsigned char*  hsbuf   = (unsigned char*)(ws + 7263232);  // 25,600,512 B (fp8 chunk-major / bf16)
    unsigned short* aggbuf  = (unsigned short*)(ws + 32863744);// 25,600,512 B (bf16 row-major)
    int*            bdata   = (int*)(ws + 58726400);           //  9,609,216 B (391*6144*4)
    int*            gcnt    = (int*)(ws + 68335616);           //      2,048 B

    // ---- setup (w2bf + grange + gcnt zero + out[NG]=0) ----
    setup_kernel<<<114, 256, 0, stream>>>(W1, W2, W3, Wb1t, Wb2t, Wb3t, batch, gstart, gcnt, out);

    // ---- CSR build ----
    bin_kernel<<<(NE + CHUNK - 1) / CHUNK, 256, 0, stream>>>(src, dst, gcnt, bdata, NE);
    csr2a_kernel<<<NBUK, 256, 0, stream>>>(gcnt, bdata, dinv, rowptr);

    // ---- layer 1: CSR scatter || gemm1 (fused); then chunked agg1 ----
    fill_gemm1_kernel<<<FILLB + GEMMB, 256, 0, stream>>>(gcnt, bdata, rowptr, csr_src,
                                                         x, Wb1t, dinv, hsbuf);
    agg8c_kernel<128><<<((NN + 127) / 128) * 4, 256, 0, stream>>>(rowptr, csr_src, hsbuf, dinv, b1, aggbuf, NN);

    // ---- layer 2 ----
    mfma_gemm<128, 64, true, true, true><<<GEMMB, 256, 0, stream>>>(aggbuf, Wb2t, dinv, hsbuf, NN, GEMMB * 4);
    agg8c_kernel<64><<<((NN + 127) / 128) * 2, 256, 0, stream>>>(rowptr, csr_src, hsbuf, dinv, b2, aggbuf, NN);

    // ---- layer 3: gemm (bf16 row-major out); fused agg+pool+logit+loss ----
    mfma_gemm<64, 32, true, true, false><<<GEMMB, 256, 0, stream>>>(aggbuf, Wb3t, dinv, hsbuf, NN, GEMMB * 4);
    aggpool_kernel<<<NG, 256, 0, stream>>>(rowptr, csr_src, (const unsigned short*)hsbuf,
                                           dinv, b3, gstart, Wl, bl, targets, out);
}

// Round 13
// 309.831 us; speedup vs baseline: 1.0774x; 1.0774x over previous
//
#include <hip/hip_runtime.h>
#include <math.h>

#define NN 100000
#define NE 1600000
#define NG 2048
#define NBUK 391     // ceil(NN/256) dst-buckets, bucket = dst >> 8
#define SLOT 6144    // per-bucket capacity: mean 4096 + 32 sigma
#define CHUNK 8192   // edges per bin block
#define FILLB 391    // fill-path blocks in fused kernel
#define GEMMB 832    // gemm blocks (3328 waves, ~1.9 m-tiles/wave)

typedef __attribute__((ext_vector_type(8))) short short8;
typedef __attribute__((ext_vector_type(8))) __bf16 bf16x8;
typedef __attribute__((ext_vector_type(4))) float f32x4;
typedef __attribute__((ext_vector_type(2))) float f32x2;
typedef __attribute__((ext_vector_type(4))) unsigned int uint4_;

__device__ __forceinline__ unsigned short f2bf(float f) {       // RNE, finite inputs
    unsigned int u = __float_as_uint(f);
    return (unsigned short)((u + 0x7FFFu + ((u >> 16) & 1u)) >> 16);
}
__device__ __forceinline__ float bf2f(unsigned short s) {
    return __uint_as_float(((unsigned int)s) << 16);
}
__device__ __forceinline__ unsigned char f2fp8(float v) {       // HW cvt, e4m3fn
    int p = __builtin_amdgcn_cvt_pk_fp8_f32(v, v, 0, false);
    return (unsigned char)(p & 0xFF);
}

// ---------------- setup: w2bf (transposed) + grange + gcnt zero + loss-slot zero ----------------
__global__ __launch_bounds__(256) void setup_kernel(const float* __restrict__ W1,
                                                    const float* __restrict__ W2,
                                                    const float* __restrict__ W3,
                                                    unsigned short* __restrict__ Wb1t,
                                                    unsigned short* __restrict__ Wb2t,
                                                    unsigned short* __restrict__ Wb3t,
                                                    const int* __restrict__ batch,
                                                    int* __restrict__ gstart,
                                                    int* __restrict__ gcnt,
                                                    float* __restrict__ out) {
    const int bid = blockIdx.x, t = threadIdx.x;
    if (bid < 104) {                                  // weight cvt+transpose (26624 elems)
        int i = bid * 256 + t;
        if (i < 16384) {                              // W1: 128x128
            int k = i >> 7, c = i & 127;
            Wb1t[c * 128 + k] = f2bf(W1[i]);
        } else if (i < 24576) {                       // W2: 128x64
            int j = i - 16384; int k = j >> 6, c = j & 63;
            Wb2t[c * 128 + k] = f2bf(W2[j]);
        } else if (i < 26624) {                       // W3: 64x32
            int j = i - 24576; int k = j >> 5, c = j & 31;
            Wb3t[c * 64 + k] = f2bf(W3[j]);
        }
    } else if (bid < 113) {                           // grange (batch sorted)
        int g = (bid - 104) * 256 + t;
        if (g > NG) return;
        if (g == NG) { gstart[g] = NN; return; }
        int lo = 0, hi = NN;
        while (lo < hi) { int mid = (lo + hi) >> 1; if (batch[mid] < g) lo = mid + 1; else hi = mid; }
        gstart[g] = lo;
    } else {                                          // zero gcnt (512 ints) + loss accumulator
        gcnt[t] = 0; gcnt[t + 256] = 0;
        if (t == 0) out[NG] = 0.0f;
    }
}

// ---------------- pass 1: bin edges by dst>>8, bucket-sorted block appends ----------------
__global__ __launch_bounds__(256) void bin_kernel(const int* __restrict__ src,
                                                  const int* __restrict__ dst,
                                                  int* __restrict__ gcnt,
                                                  int* __restrict__ bucket_data, int E) {
    __shared__ int cnt[512];                 // padded scan array
    __shared__ int offs[NBUK];
    __shared__ int cnt2[NBUK];
    __shared__ int gb[NBUK];
    __shared__ int packB[CHUNK];
    __shared__ unsigned short bktB[CHUNK];
    const int t = threadIdx.x;
    const int E0 = blockIdx.x * CHUNK;
    const int valid = min(CHUNK, E - E0);
    cnt[t] = 0; cnt[t + 256] = 0;
    for (int i = t; i < NBUK; i += 256) cnt2[i] = 0;
    __syncthreads();
    // A: count buckets
    for (int i = t; i < valid; i += 256)
        atomicAdd(&cnt[dst[E0 + i] >> 8], 1);
    __syncthreads();
    int o0 = cnt[t], o1 = cnt[t + 256];
    // B: inclusive Hillis-Steele scan over 512 (2 elems/thread)
    for (int off = 1; off < 512; off <<= 1) {
        int a0 = (t >= off) ? cnt[t - off] : 0;
        int a1 = (t + 256 >= off) ? cnt[t + 256 - off] : 0;
        __syncthreads();
        cnt[t] += a0; cnt[t + 256] += a1;
        __syncthreads();
    }
    if (t < NBUK)       { offs[t] = cnt[t] - o0;             gb[t] = o0 ? atomicAdd(&gcnt[t], o0) : 0; }
    if (t + 256 < NBUK) { offs[t + 256] = cnt[t + 256] - o1; gb[t + 256] = o1 ? atomicAdd(&gcnt[t + 256], o1) : 0; }
    __syncthreads();
    // C: re-read edges, place bucket-sorted into LDS
    for (int i = t; i < valid; i += 256) {
        int s = src[E0 + i], d = dst[E0 + i];
        int b = d >> 8;
        int pos = offs[b] + atomicAdd(&cnt2[b], 1);
        packB[pos] = (s << 8) | (d & 255);
        bktB[pos] = (unsigned short)b;
    }
    __syncthreads();
    // D: contiguous-per-bucket append to global streams
    for (int i = t; i < valid; i += 256) {
        int b = bktB[i];
        int idx = gb[b] + (i - offs[b]);
        if (idx < SLOT) bucket_data[b * SLOT + idx] = packB[i];
    }
}

// ---------------- pass 2a: per-bucket counts -> dinv + rowptr (base scanned inline) ----------------
__global__ __launch_bounds__(256) void csr2a_kernel(const int* __restrict__ gcnt,
                                                    const int* __restrict__ bucket_data,
                                                    float* __restrict__ dinv,
                                                    int* __restrict__ rowptr) {
    __shared__ int bs[512];
    __shared__ int counts[256];
    __shared__ int base_sh;
    const int t = threadIdx.x;
    const int b = blockIdx.x;
    // inline exclusive scan of min(gcnt,SLOT) over all buckets (redundant per block)
    bs[t] = (t < NBUK) ? min(gcnt[t], SLOT) : 0;
    bs[t + 256] = (t + 256 < NBUK) ? min(gcnt[t + 256], SLOT) : 0;
    counts[t] = 0;
    __syncthreads();
    for (int off = 1; off < 512; off <<= 1) {
        int a0 = (t >= off) ? bs[t - off] : 0;
        int a1 = (t + 256 >= off) ? bs[t + 256 - off] : 0;
        __syncthreads();
        bs[t] += a0; bs[t + 256] += a1;
        __syncthreads();
    }
    if (t == 0) base_sh = bs[b] - min(gcnt[b], SLOT);   // exclusive base
    __syncthreads();
    const int cb = min(gcnt[b], SLOT);
    const int* bd = bucket_data + b * SLOT;
    for (int i = t; i < cb; i += 256) atomicAdd(&counts[bd[i] & 255], 1);
    __syncthreads();
    int c = counts[t];
    for (int off = 1; off < 256; off <<= 1) {
        int a = (t >= off) ? counts[t - off] : 0;
        __syncthreads();
        counts[t] += a;
        __syncthreads();
    }
    int excl = counts[t] - c;
    int node = b * 256 + t;
    if (node < NN) {
        dinv[node] = rsqrtf((float)c + 1.0f);
        rowptr[node] = base_sh + excl;
    }
    if (b == NBUK - 1 && t == 0) rowptr[NN] = NE;
}

// ---------------- MFMA GEMM body ----------------
// One wave per 16-row m-tile computing ALL FOUT cols; grid-stride with register
// double-buffer: next A-tile loads issue BEFORE current tile's MFMA block.
// OUT_FP8: hs written ROW-MAJOR fp8 (chunk-major regressed — R12: divergence cost
// beat the FETCH win; gather is issue-bound at ~2 TB/s, not BW-bound).
// Layouts [m89-verified]: A: m=lane&15, k=quad*8+j ; B: n=lane&15, k=quad*8+j ;
//                         C/D: col=lane&15, row=quad*4+reg.
template<int FIN, int FOUT, bool RELU_IN, bool A_BF16, bool OUT_FP8>
__device__ __forceinline__ void gemm_body(const void* __restrict__ in_,
                                          const unsigned short* __restrict__ Wbt,
                                          const float* __restrict__ dinv,
                                          void* __restrict__ out,
                                          int N, int nwaves, int wid, int lane) {
    constexpr int NT = FOUT / 16;
    constexpr int KS = FIN / 32;
    const int m16  = lane & 15;
    const int quad = lane >> 4;
    const int koff = quad * 8;

    short8 bfrag[NT][KS];
#pragma unroll
    for (int nt = 0; nt < NT; ++nt) {
        const unsigned short* wcol = Wbt + (size_t)(m16 + nt * 16) * FIN + koff;
#pragma unroll
        for (int ks = 0; ks < KS; ++ks)
            bfrag[nt][ks] = *(const short8*)(wcol + ks * 32);
    }

    const int MT = N / 16;                 // N == 100000 -> exact
    int mt = wid;
    if (mt >= MT) return;

    short8 curB[KS], nxtB[KS];
    f32x4  curF[KS][2], nxtF[KS][2];

    auto load_raw = [&](int m, short8* rb, f32x4 (*rf)[2]) {
        const int row = m * 16 + m16;
        if (A_BF16) {
            const unsigned short* A = (const unsigned short*)in_ + (size_t)row * FIN + koff;
#pragma unroll
            for (int ks = 0; ks < KS; ++ks) rb[ks] = *(const short8*)(A + ks * 32);
        } else {
            const float* A = (const float*)in_ + (size_t)row * FIN + koff;
#pragma unroll
            for (int ks = 0; ks < KS; ++ks) {
                rf[ks][0] = *(const f32x4*)(A + ks * 32);
                rf[ks][1] = *(const f32x4*)(A + ks * 32 + 4);
            }
        }
    };

    load_raw(mt, curB, curF);
    while (true) {
        const int mtn = mt + nwaves;
        const bool have_next = (mtn < MT);
        if (have_next) load_raw(mtn, nxtB, nxtF);   // in flight across the MFMAs below

        short8 afrag[KS];
        if (A_BF16) {
#pragma unroll
            for (int ks = 0; ks < KS; ++ks) {
                short8 a = curB[ks];
                if (RELU_IN) {
#pragma unroll
                    for (int j = 0; j < 8; ++j)
                        a[j] = (short)(((unsigned short)a[j] & 0x8000u) ? 0 : (unsigned short)a[j]);
                }
                afrag[ks] = a;
            }
        } else {
#pragma unroll
            for (int ks = 0; ks < KS; ++ks) {
#pragma unroll
                for (int j = 0; j < 4; ++j) {
                    float a0 = curF[ks][0][j], a1 = curF[ks][1][j];
                    if (RELU_IN) { a0 = fmaxf(a0, 0.f); a1 = fmaxf(a1, 0.f); }
                    afrag[ks][j]     = (short)f2bf(a0);
                    afrag[ks][j + 4] = (short)f2bf(a1);
                }
            }
        }

        f32x4 acc[NT];
#pragma unroll
        for (int nt = 0; nt < NT; ++nt) acc[nt] = (f32x4){0.f, 0.f, 0.f, 0.f};
#pragma unroll
        for (int nt = 0; nt < NT; ++nt)
#pragma unroll
            for (int ks = 0; ks < KS; ++ks)
                acc[nt] = __builtin_amdgcn_mfma_f32_16x16x32_bf16(
                    __builtin_bit_cast(bf16x8, afrag[ks]),
                    __builtin_bit_cast(bf16x8, bfrag[nt][ks]), acc[nt], 0, 0, 0);

        float dv[4];
#pragma unroll
        for (int r = 0; r < 4; ++r) dv[r] = dinv[mt * 16 + quad * 4 + r];
#pragma unroll
        for (int nt = 0; nt < NT; ++nt) {
            const int col = m16 + nt * 16;
#pragma unroll
            for (int r = 0; r < 4; ++r) {
                int orow = mt * 16 + quad * 4 + r;
                float v = acc[nt][r] * dv[r];
                if (OUT_FP8)
                    ((unsigned char*)out)[(size_t)orow * FOUT + col] = f2fp8(v);
                else
                    ((unsigned short*)out)[(size_t)orow * FOUT + col] = f2bf(v);
            }
        }

        if (!have_next) break;
#pragma unroll
        for (int ks = 0; ks < KS; ++ks) {
            curB[ks] = nxtB[ks];
            curF[ks][0] = nxtF[ks][0];
            curF[ks][1] = nxtF[ks][1];
        }
        mt = mtn;
    }
}

// ---------------- fused: CSR fine-scatter (blocks 0..390) || gemm1 (rest) ----------------
__global__ __launch_bounds__(256, 2) void fill_gemm1_kernel(const int* __restrict__ gcnt,
                                                            const int* __restrict__ bucket_data,
                                                            const int* __restrict__ rowptr,
                                                            int* __restrict__ csr_src,
                                                            const float* __restrict__ x,
                                                            const unsigned short* __restrict__ Wb1t,
                                                            const float* __restrict__ dinv,
                                                            unsigned char* __restrict__ hs) {
    __shared__ int offs[256];
    __shared__ int cnt2[256];
    const int t = threadIdx.x;
    if (blockIdx.x < FILLB) {
        const int b = blockIdx.x;
        const int cb = min(gcnt[b], SLOT);
        const int* bd = bucket_data + b * SLOT;
        int node = b * 256 + t;
        offs[t] = (node < NN) ? rowptr[node] : 0;
        cnt2[t] = 0;
        __syncthreads();
        for (int i = t; i < cb; i += 256) {
            int p = bd[i];
            int local = p & 255;
            int pos = atomicAdd(&cnt2[local], 1);
            csr_src[offs[local] + pos] = p >> 8;   // p>=0, arith shift ok
        }
    } else {
        const int wid = ((blockIdx.x - FILLB) * 256 + t) >> 6;
        gemm_body<128, 128, false, false, true>(x, Wb1t, dinv, hs, NN, GEMMB * 4, wid, t & 63);
    }
}

// ---------------- standalone GEMMs (layers 2,3) ----------------
template<int FIN, int FOUT, bool RELU_IN, bool A_BF16, bool OUT_FP8>
__global__ __launch_bounds__(256, 2) void mfma_gemm(const void* __restrict__ in_,
                                                    const unsigned short* __restrict__ Wbt,
                                                    const float* __restrict__ dinv,
                                                    void* __restrict__ out,
                                                    int N, int nwaves) {
    const int wid = (blockIdx.x * 256 + threadIdx.x) >> 6;
    gemm_body<FIN, FOUT, RELU_IN, A_BF16, OUT_FP8>(in_, Wbt, dinv, out, N, nwaves, wid, threadIdx.x & 63);
}

// ---------------- fp8 gather-aggregate: agg[n] = dinv[n]*(hs[n] + sum_e hs[src]) + b ----------------
// hs is fp8 e4m3 row-major [N][F]; lane covers 16 cols (16 B load); x4 edge unroll.
// Output bf16 row-major (next GEMM's A input).
template<int F>
__global__ __launch_bounds__(256) void agg8_kernel(const int* __restrict__ rowptr,
                                                   const int* __restrict__ csr_src,
                                                   const unsigned char* __restrict__ hs,
                                                   const float* __restrict__ dinv,
                                                   const float* __restrict__ b,
                                                   unsigned short* __restrict__ aggout, int N) {
    constexpr int TPN = F / 16;          // lanes per node (16 fp8 = 16 B each)
    constexpr int NPB = 256 / TPN;
    const int n = blockIdx.x * NPB + threadIdx.x / TPN;
    const int c16 = (threadIdx.x % TPN) * 16;
    if (n >= N) return;
    const uint4_* hp = (const uint4_*)hs;            // row = F/16 uint4
    const int lanep = c16 / 16;
    const int rstride = F / 16;
    int row = rowptr[n], end = rowptr[n + 1];
    float acc[16];
    {
        uint4_ u = hp[(size_t)n * rstride + lanep];   // self term
#pragma unroll
        for (int w = 0; w < 4; ++w) {
            f32x2 lo = __builtin_amdgcn_cvt_pk_f32_fp8(u[w], false);
            f32x2 hi = __builtin_amdgcn_cvt_pk_f32_fp8(u[w], true);
            acc[w * 4 + 0] = lo[0]; acc[w * 4 + 1] = lo[1];
            acc[w * 4 + 2] = hi[0]; acc[w * 4 + 3] = hi[1];
        }
    }
    int j = row;
    for (; j + 4 <= end; j += 4) {
        int s0 = csr_src[j], s1 = csr_src[j + 1], s2 = csr_src[j + 2], s3 = csr_src[j + 3];
        uint4_ u0 = hp[(size_t)s0 * rstride + lanep];
        uint4_ u1 = hp[(size_t)s1 * rstride + lanep];
        uint4_ u2 = hp[(size_t)s2 * rstride + lanep];
        uint4_ u3 = hp[(size_t)s3 * rstride + lanep];
#pragma unroll
        for (int w = 0; w < 4; ++w) {
            f32x2 a0 = __builtin_amdgcn_cvt_pk_f32_fp8(u0[w], false);
            f32x2 b0 = __builtin_amdgcn_cvt_pk_f32_fp8(u0[w], true);
            f32x2 a1 = __builtin_amdgcn_cvt_pk_f32_fp8(u1[w], false);
            f32x2 b1 = __builtin_amdgcn_cvt_pk_f32_fp8(u1[w], true);
            f32x2 a2 = __builtin_amdgcn_cvt_pk_f32_fp8(u2[w], false);
            f32x2 b2 = __builtin_amdgcn_cvt_pk_f32_fp8(u2[w], true);
            f32x2 a3 = __builtin_amdgcn_cvt_pk_f32_fp8(u3[w], false);
            f32x2 b3 = __builtin_amdgcn_cvt_pk_f32_fp8(u3[w], true);
            acc[w * 4 + 0] += (a0[0] + a1[0]) + (a2[0] + a3[0]);
            acc[w * 4 + 1] += (a0[1] + a1[1]) + (a2[1] + a3[1]);
            acc[w * 4 + 2] += (b0[0] + b1[0]) + (b2[0] + b3[0]);
            acc[w * 4 + 3] += (b0[1] + b1[1]) + (b2[1] + b3[1]);
        }
    }
    for (; j < end; ++j) {
        uint4_ u = hp[(size_t)csr_src[j] * rstride + lanep];
#pragma unroll
        for (int w = 0; w < 4; ++w) {
            f32x2 lo = __builtin_amdgcn_cvt_pk_f32_fp8(u[w], false);
            f32x2 hi = __builtin_amdgcn_cvt_pk_f32_fp8(u[w], true);
            acc[w * 4 + 0] += lo[0]; acc[w * 4 + 1] += lo[1];
            acc[w * 4 + 2] += hi[0]; acc[w * 4 + 3] += hi[1];
        }
    }
    float c = dinv[n];
    short8 o0, o1;
#pragma unroll
    for (int k = 0; k < 8; ++k) {
        o0[k] = (short)f2bf(fmaf(acc[k], c, b[c16 + k]));
        o1[k] = (short)f2bf(fmaf(acc[k + 8], c, b[c16 + 8 + k]));
    }
    unsigned short* op = aggout + (size_t)n * F + c16;
    *(short8*)op = o0;
    *(short8*)(op + 8) = o1;
}

// ---------------- fused layer-3 tail: gather-agg + mean-pool + logit + BCE ----------------
// One block per graph (batch sorted -> nodes [gstart[g], gstart[g+1]) contiguous).
// hs3 is bf16 row-major [N][32]. out[g]=sigmoid(logit); out[NG] += loss/NG (atomic).
__global__ __launch_bounds__(256) void aggpool_kernel(const int* __restrict__ rowptr,
                                                      const int* __restrict__ csr_src,
                                                      const unsigned short* __restrict__ hs,
                                                      const float* __restrict__ dinv,
                                                      const float* __restrict__ b,
                                                      const int* __restrict__ gstart,
                                                      const float* __restrict__ Wl,
                                                      const float* __restrict__ bl,
                                                      const int* __restrict__ targets,
                                                      float* __restrict__ out) {
    constexpr int F = 32;
    __shared__ float sm[64][33];                      // 64 node-slots x 32 cols (+pad)
    const int g = blockIdx.x;
    const int s = gstart[g], e = gstart[g + 1];
    const int slot = threadIdx.x >> 2;                // 0..63
    const int c8 = (threadIdx.x & 3) * 8;
    float accp[8];
#pragma unroll
    for (int k = 0; k < 8; ++k) accp[k] = 0.f;
    for (int n = s + slot; n < e; n += 64) {
        int row = rowptr[n], end = rowptr[n + 1];
        float acc[8];
        {
            short8 h = *(const short8*)(hs + (size_t)n * F + c8);   // self term
#pragma unroll
            for (int k = 0; k < 8; ++k) acc[k] = bf2f((unsigned short)h[k]);
        }
        int j = row;
        for (; j + 4 <= end; j += 4) {
            int s0 = csr_src[j], s1 = csr_src[j + 1], s2 = csr_src[j + 2], s3 = csr_src[j + 3];
            short8 h0 = *(const short8*)(hs + (size_t)s0 * F + c8);
            short8 h1 = *(const short8*)(hs + (size_t)s1 * F + c8);
            short8 h2 = *(const short8*)(hs + (size_t)s2 * F + c8);
            short8 h3 = *(const short8*)(hs + (size_t)s3 * F + c8);
#pragma unroll
            for (int k = 0; k < 8; ++k)
                acc[k] += (bf2f((unsigned short)h0[k]) + bf2f((unsigned short)h1[k])) +
                          (bf2f((unsigned short)h2[k]) + bf2f((unsigned short)h3[k]));
        }
        for (; j < end; ++j) {
            short8 h = *(const short8*)(hs + (size_t)csr_src[j] * F + c8);
#pragma unroll
            for (int k = 0; k < 8; ++k) acc[k] += bf2f((unsigned short)h[k]);
        }
        float c = dinv[n];
#pragma unroll
        for (int k = 0; k < 8; ++k) accp[k] += fmaf(acc[k], c, b[c8 + k]);
    }
#pragma unroll
    for (int k = 0; k < 8; ++k) sm[slot][c8 + k] = accp[k];
    __syncthreads();
    // reduce 64 slots -> 8 -> 1
    const int col = threadIdx.x & 31, part = threadIdx.x >> 5;
    float v = 0.f;
    for (int ss = part * 8; ss < part * 8 + 8; ++ss) v += sm[ss][col];
    __syncthreads();
    sm[part][col] = v;
    __syncthreads();
    if (threadIdx.x < 32) {
        float tot = 0.f;
        for (int p = 0; p < 8; ++p) tot += sm[p][threadIdx.x];
        float cnt = fmaxf((float)(e - s), 1.0f);
        sm[8][threadIdx.x] = (tot / cnt) * Wl[threadIdx.x];
    }
    __syncthreads();
    if (threadIdx.x == 0) {
        float logit = bl[0];
        for (int k = 0; k < 32; ++k) logit += sm[8][k];
        out[g] = 1.0f / (1.0f + expf(-logit));
        float y = (float)targets[g];
        float l = fmaxf(logit, 0.0f) - logit * y + log1pf(expf(-fabsf(logit)));
        atomicAdd(out + NG, l / (float)NG);
    }
}

extern "C" void kernel_launch(void* const* d_in, const int* in_sizes, int n_in,
                              void* d_out, int out_size, void* d_ws, size_t ws_size,
                              hipStream_t stream) {
    const float* x       = (const float*)d_in[0];
    const int*   ei      = (const int*)d_in[1];
    const int*   batch   = (const int*)d_in[2];
    const int*   targets = (const int*)d_in[3];
    const float* W1 = (const float*)d_in[4];
    const float* b1 = (const float*)d_in[5];
    const float* W2 = (const float*)d_in[6];
    const float* b2 = (const float*)d_in[7];
    const float* W3 = (const float*)d_in[8];
    const float* b3 = (const float*)d_in[9];
    const float* Wl = (const float*)d_in[10];
    const float* bl = (const float*)d_in[11];
    float* out = (float*)d_out;
    char*  ws  = (char*)d_ws;

    const int* src = ei;
    const int* dst = ei + NE;

    // workspace layout (byte offsets, 512B aligned) — total ~68.3 MB
    float*          dinv    = (float*)(ws);                    //    400,384 B
    int*            rowptr  = (int*)(ws + 400384);             //    400,384 B (NN+1)
    int*            csr_src = (int*)(ws + 800768);             //  6,400,512 B
    unsigned short* Wb1t    = (unsigned short*)(ws + 7201280); //     32,768 B (transposed)
    unsigned short* Wb2t    = (unsigned short*)(ws + 7234048); //     16,384 B (transposed)
    unsigned short* Wb3t    = (unsigned short*)(ws + 7250432); //      4,096 B (transposed)
    int*            gstart  = (int*)(ws + 7254528);            //      8,704 B (NG+1)
    unsigned char*  hsbuf   = (unsigned char*)(ws + 7263232);  // 25,600,512 B (fp8 / bf16 row-major)
    unsigned short* aggbuf  = (unsigned short*)(ws + 32863744);// 25,600,512 B (bf16 row-major)
    int*            bdata   = (int*)(ws + 58726400);           //  9,609,216 B (391*6144*4)
    int*            gcnt    = (int*)(ws + 68335616);           //      2,048 B

    // ---- setup (w2bf + grange + gcnt zero + out[NG]=0) ----
    setup_kernel<<<114, 256, 0, stream>>>(W1, W2, W3, Wb1t, Wb2t, Wb3t, batch, gstart, gcnt, out);

    // ---- CSR build ----
    bin_kernel<<<(NE + CHUNK - 1) / CHUNK, 256, 0, stream>>>(src, dst, gcnt, bdata, NE);
    csr2a_kernel<<<NBUK, 256, 0, stream>>>(gcnt, bdata, dinv, rowptr);

    // ---- layer 1: CSR scatter || gemm1 (fused); then agg1 ----
    fill_gemm1_kernel<<<FILLB + GEMMB, 256, 0, stream>>>(gcnt, bdata, rowptr, csr_src,
                                                         x, Wb1t, dinv, hsbuf);
    agg8_kernel<128><<<(NN + 31) / 32, 256, 0, stream>>>(rowptr, csr_src, hsbuf, dinv, b1, aggbuf, NN);

    // ---- layer 2 ----
    mfma_gemm<128, 64, true, true, true><<<GEMMB, 256, 0, stream>>>(aggbuf, Wb2t, dinv, hsbuf, NN, GEMMB * 4);
    agg8_kernel<64><<<(NN + 63) / 64, 256, 0, stream>>>(rowptr, csr_src, hsbuf, dinv, b2, aggbuf, NN);

    // ---- layer 3: gemm (bf16 row-major out); fused agg+pool+logit+loss ----
    mfma_gemm<64, 32, true, true, false><<<GEMMB, 256, 0, stream>>>(aggbuf, Wb3t, dinv, hsbuf, NN, GEMMB * 4);
    aggpool_kernel<<<NG, 256, 0, stream>>>(rowptr, csr_src, (const unsigned short*)hsbuf,
                                           dinv, b3, gstart, Wl, bl, targets, out);
}

// Round 14
// 303.820 us; speedup vs baseline: 1.0988x; 1.0198x over previous
//
#include <hip/hip_runtime.h>
#include <math.h>

#define NN 100000
#define NE 1600000
#define NG 2048
#define NBUK 391     // ceil(NN/256) dst-buckets, bucket = dst >> 8
#define SLOT 6144    // per-bucket capacity: mean 4096 + 32 sigma
#define CHUNK 8192   // edges per bin block
#define FILLB 391    // fill-path blocks in fused kernel
#define GEMMB 832    // gemm blocks (3328 waves, ~1.9 m-tiles/wave)

typedef __attribute__((ext_vector_type(8))) short short8;
typedef __attribute__((ext_vector_type(8))) __bf16 bf16x8;
typedef __attribute__((ext_vector_type(4))) float f32x4;
typedef __attribute__((ext_vector_type(2))) float f32x2;
typedef __attribute__((ext_vector_type(4))) unsigned int uint4_;

__device__ __forceinline__ unsigned short f2bf(float f) {       // RNE, finite inputs
    unsigned int u = __float_as_uint(f);
    return (unsigned short)((u + 0x7FFFu + ((u >> 16) & 1u)) >> 16);
}
__device__ __forceinline__ float bf2f(unsigned short s) {
    return __uint_as_float(((unsigned int)s) << 16);
}
__device__ __forceinline__ unsigned char f2fp8(float v) {       // HW cvt, e4m3fn
    int p = __builtin_amdgcn_cvt_pk_fp8_f32(v, v, 0, false);
    return (unsigned char)(p & 0xFF);
}

// ---------------- setup: w2bf (transposed) + grange + gcnt zero + sums zero ----------------
__global__ __launch_bounds__(256) void setup_kernel(const float* __restrict__ W1,
                                                    const float* __restrict__ W2,
                                                    const float* __restrict__ W3,
                                                    unsigned short* __restrict__ Wb1t,
                                                    unsigned short* __restrict__ Wb2t,
                                                    unsigned short* __restrict__ Wb3t,
                                                    const int* __restrict__ batch,
                                                    int* __restrict__ gstart,
                                                    int* __restrict__ gcnt,
                                                    float* __restrict__ sums) {
    const int bid = blockIdx.x, t = threadIdx.x;
    if (bid < 104) {                                  // weight cvt+transpose (26624 elems)
        int i = bid * 256 + t;
        if (i < 16384) {                              // W1: 128x128
            int k = i >> 7, c = i & 127;
            Wb1t[c * 128 + k] = f2bf(W1[i]);
        } else if (i < 24576) {                       // W2: 128x64
            int j = i - 16384; int k = j >> 6, c = j & 63;
            Wb2t[c * 128 + k] = f2bf(W2[j]);
        } else if (i < 26624) {                       // W3: 64x32
            int j = i - 24576; int k = j >> 5, c = j & 31;
            Wb3t[c * 64 + k] = f2bf(W3[j]);
        }
    } else if (bid < 113) {                           // grange (batch sorted)
        int g = (bid - 104) * 256 + t;
        if (g > NG) return;
        if (g == NG) { gstart[g] = NN; return; }
        int lo = 0, hi = NN;
        while (lo < hi) { int mid = (lo + hi) >> 1; if (batch[mid] < g) lo = mid + 1; else hi = mid; }
        gstart[g] = lo;
    } else if (bid < 114) {                           // zero gcnt (512 ints)
        gcnt[t] = 0; gcnt[t + 256] = 0;
    } else {                                          // zero sums (65536 floats, 256 blocks)
        sums[(bid - 114) * 256 + t] = 0.0f;
    }
}

// ---------------- pass 1: bin edges by dst>>8, bucket-sorted block appends ----------------
__global__ __launch_bounds__(256) void bin_kernel(const int* __restrict__ src,
                                                  const int* __restrict__ dst,
                                                  int* __restrict__ gcnt,
                                                  int* __restrict__ bucket_data, int E) {
    __shared__ int cnt[512];                 // padded scan array
    __shared__ int offs[NBUK];
    __shared__ int cnt2[NBUK];
    __shared__ int gb[NBUK];
    __shared__ int packB[CHUNK];
    __shared__ unsigned short bktB[CHUNK];
    const int t = threadIdx.x;
    const int E0 = blockIdx.x * CHUNK;
    const int valid = min(CHUNK, E - E0);
    cnt[t] = 0; cnt[t + 256] = 0;
    for (int i = t; i < NBUK; i += 256) cnt2[i] = 0;
    __syncthreads();
    // A: count buckets
    for (int i = t; i < valid; i += 256)
        atomicAdd(&cnt[dst[E0 + i] >> 8], 1);
    __syncthreads();
    int o0 = cnt[t], o1 = cnt[t + 256];
    // B: inclusive Hillis-Steele scan over 512 (2 elems/thread)
    for (int off = 1; off < 512; off <<= 1) {
        int a0 = (t >= off) ? cnt[t - off] : 0;
        int a1 = (t + 256 >= off) ? cnt[t + 256 - off] : 0;
        __syncthreads();
        cnt[t] += a0; cnt[t + 256] += a1;
        __syncthreads();
    }
    if (t < NBUK)       { offs[t] = cnt[t] - o0;             gb[t] = o0 ? atomicAdd(&gcnt[t], o0) : 0; }
    if (t + 256 < NBUK) { offs[t + 256] = cnt[t + 256] - o1; gb[t + 256] = o1 ? atomicAdd(&gcnt[t + 256], o1) : 0; }
    __syncthreads();
    // C: re-read edges, place bucket-sorted into LDS
    for (int i = t; i < valid; i += 256) {
        int s = src[E0 + i], d = dst[E0 + i];
        int b = d >> 8;
        int pos = offs[b] + atomicAdd(&cnt2[b], 1);
        packB[pos] = (s << 8) | (d & 255);
        bktB[pos] = (unsigned short)b;
    }
    __syncthreads();
    // D: contiguous-per-bucket append to global streams
    for (int i = t; i < valid; i += 256) {
        int b = bktB[i];
        int idx = gb[b] + (i - offs[b]);
        if (idx < SLOT) bucket_data[b * SLOT + idx] = packB[i];
    }
}

// ---------------- pass 2a: per-bucket counts -> dinv + rowptr (base scanned inline) ----------------
__global__ __launch_bounds__(256) void csr2a_kernel(const int* __restrict__ gcnt,
                                                    const int* __restrict__ bucket_data,
                                                    float* __restrict__ dinv,
                                                    int* __restrict__ rowptr) {
    __shared__ int bs[512];
    __shared__ int counts[256];
    __shared__ int base_sh;
    const int t = threadIdx.x;
    const int b = blockIdx.x;
    // inline exclusive scan of min(gcnt,SLOT) over all buckets (redundant per block)
    bs[t] = (t < NBUK) ? min(gcnt[t], SLOT) : 0;
    bs[t + 256] = (t + 256 < NBUK) ? min(gcnt[t + 256], SLOT) : 0;
    counts[t] = 0;
    __syncthreads();
    for (int off = 1; off < 512; off <<= 1) {
        int a0 = (t >= off) ? bs[t - off] : 0;
        int a1 = (t + 256 >= off) ? bs[t + 256 - off] : 0;
        __syncthreads();
        bs[t] += a0; bs[t + 256] += a1;
        __syncthreads();
    }
    if (t == 0) base_sh = bs[b] - min(gcnt[b], SLOT);   // exclusive base
    __syncthreads();
    const int cb = min(gcnt[b], SLOT);
    const int* bd = bucket_data + b * SLOT;
    for (int i = t; i < cb; i += 256) atomicAdd(&counts[bd[i] & 255], 1);
    __syncthreads();
    int c = counts[t];
    for (int off = 1; off < 256; off <<= 1) {
        int a = (t >= off) ? counts[t - off] : 0;
        __syncthreads();
        counts[t] += a;
        __syncthreads();
    }
    int excl = counts[t] - c;
    int node = b * 256 + t;
    if (node < NN) {
        dinv[node] = rsqrtf((float)c + 1.0f);
        rowptr[node] = base_sh + excl;
    }
    if (b == NBUK - 1 && t == 0) rowptr[NN] = NE;
}

// ---------------- MFMA GEMM body ----------------
// One wave per 16-row m-tile computing ALL FOUT cols; grid-stride with register
// double-buffer: next A-tile loads issue BEFORE current tile's MFMA block.
// Layouts [m89-verified]: A: m=lane&15, k=quad*8+j ; B: n=lane&15, k=quad*8+j ;
//                         C/D: col=lane&15, row=quad*4+reg.
template<int FIN, int FOUT, bool RELU_IN, bool A_BF16, bool OUT_FP8>
__device__ __forceinline__ void gemm_body(const void* __restrict__ in_,
                                          const unsigned short* __restrict__ Wbt,
                                          const float* __restrict__ dinv,
                                          void* __restrict__ out,
                                          int N, int nwaves, int wid, int lane) {
    constexpr int NT = FOUT / 16;
    constexpr int KS = FIN / 32;
    const int m16  = lane & 15;
    const int quad = lane >> 4;
    const int koff = quad * 8;

    short8 bfrag[NT][KS];
#pragma unroll
    for (int nt = 0; nt < NT; ++nt) {
        const unsigned short* wcol = Wbt + (size_t)(m16 + nt * 16) * FIN + koff;
#pragma unroll
        for (int ks = 0; ks < KS; ++ks)
            bfrag[nt][ks] = *(const short8*)(wcol + ks * 32);
    }

    const int MT = N / 16;                 // N == 100000 -> exact
    int mt = wid;
    if (mt >= MT) return;

    short8 curB[KS], nxtB[KS];
    f32x4  curF[KS][2], nxtF[KS][2];

    auto load_raw = [&](int m, short8* rb, f32x4 (*rf)[2]) {
        const int row = m * 16 + m16;
        if (A_BF16) {
            const unsigned short* A = (const unsigned short*)in_ + (size_t)row * FIN + koff;
#pragma unroll
            for (int ks = 0; ks < KS; ++ks) rb[ks] = *(const short8*)(A + ks * 32);
        } else {
            const float* A = (const float*)in_ + (size_t)row * FIN + koff;
#pragma unroll
            for (int ks = 0; ks < KS; ++ks) {
                rf[ks][0] = *(const f32x4*)(A + ks * 32);
                rf[ks][1] = *(const f32x4*)(A + ks * 32 + 4);
            }
        }
    };

    load_raw(mt, curB, curF);
    while (true) {
        const int mtn = mt + nwaves;
        const bool have_next = (mtn < MT);
        if (have_next) load_raw(mtn, nxtB, nxtF);   // in flight across the MFMAs below

        short8 afrag[KS];
        if (A_BF16) {
#pragma unroll
            for (int ks = 0; ks < KS; ++ks) {
                short8 a = curB[ks];
                if (RELU_IN) {
#pragma unroll
                    for (int j = 0; j < 8; ++j)
                        a[j] = (short)(((unsigned short)a[j] & 0x8000u) ? 0 : (unsigned short)a[j]);
                }
                afrag[ks] = a;
            }
        } else {
#pragma unroll
            for (int ks = 0; ks < KS; ++ks) {
#pragma unroll
                for (int j = 0; j < 4; ++j) {
                    float a0 = curF[ks][0][j], a1 = curF[ks][1][j];
                    if (RELU_IN) { a0 = fmaxf(a0, 0.f); a1 = fmaxf(a1, 0.f); }
                    afrag[ks][j]     = (short)f2bf(a0);
                    afrag[ks][j + 4] = (short)f2bf(a1);
                }
            }
        }

        f32x4 acc[NT];
#pragma unroll
        for (int nt = 0; nt < NT; ++nt) acc[nt] = (f32x4){0.f, 0.f, 0.f, 0.f};
#pragma unroll
        for (int nt = 0; nt < NT; ++nt)
#pragma unroll
            for (int ks = 0; ks < KS; ++ks)
                acc[nt] = __builtin_amdgcn_mfma_f32_16x16x32_bf16(
                    __builtin_bit_cast(bf16x8, afrag[ks]),
                    __builtin_bit_cast(bf16x8, bfrag[nt][ks]), acc[nt], 0, 0, 0);

        float dv[4];
#pragma unroll
        for (int r = 0; r < 4; ++r) dv[r] = dinv[mt * 16 + quad * 4 + r];
#pragma unroll
        for (int nt = 0; nt < NT; ++nt) {
            const int col = m16 + nt * 16;
#pragma unroll
            for (int r = 0; r < 4; ++r) {
                int orow = mt * 16 + quad * 4 + r;
                float v = acc[nt][r] * dv[r];
                if (OUT_FP8)
                    ((unsigned char*)out)[(size_t)orow * FOUT + col] = f2fp8(v);
                else
                    ((unsigned short*)out)[(size_t)orow * FOUT + col] = f2bf(v);
            }
        }

        if (!have_next) break;
#pragma unroll
        for (int ks = 0; ks < KS; ++ks) {
            curB[ks] = nxtB[ks];
            curF[ks][0] = nxtF[ks][0];
            curF[ks][1] = nxtF[ks][1];
        }
        mt = mtn;
    }
}

// ---------------- fused: CSR fine-scatter (blocks 0..390) || gemm1 (rest) ----------------
__global__ __launch_bounds__(256, 2) void fill_gemm1_kernel(const int* __restrict__ gcnt,
                                                            const int* __restrict__ bucket_data,
                                                            const int* __restrict__ rowptr,
                                                            int* __restrict__ csr_src,
                                                            const float* __restrict__ x,
                                                            const unsigned short* __restrict__ Wb1t,
                                                            const float* __restrict__ dinv,
                                                            unsigned char* __restrict__ hs) {
    __shared__ int offs[256];
    __shared__ int cnt2[256];
    const int t = threadIdx.x;
    if (blockIdx.x < FILLB) {
        const int b = blockIdx.x;
        const int cb = min(gcnt[b], SLOT);
        const int* bd = bucket_data + b * SLOT;
        int node = b * 256 + t;
        offs[t] = (node < NN) ? rowptr[node] : 0;
        cnt2[t] = 0;
        __syncthreads();
        for (int i = t; i < cb; i += 256) {
            int p = bd[i];
            int local = p & 255;
            int pos = atomicAdd(&cnt2[local], 1);
            csr_src[offs[local] + pos] = p >> 8;   // p>=0, arith shift ok
        }
    } else {
        const int wid = ((blockIdx.x - FILLB) * 256 + t) >> 6;
        gemm_body<128, 128, false, false, true>(x, Wb1t, dinv, hs, NN, GEMMB * 4, wid, t & 63);
    }
}

// ---------------- standalone GEMMs (layers 2,3) ----------------
template<int FIN, int FOUT, bool RELU_IN, bool A_BF16, bool OUT_FP8>
__global__ __launch_bounds__(256, 2) void mfma_gemm(const void* __restrict__ in_,
                                                    const unsigned short* __restrict__ Wbt,
                                                    const float* __restrict__ dinv,
                                                    void* __restrict__ out,
                                                    int N, int nwaves) {
    const int wid = (blockIdx.x * 256 + threadIdx.x) >> 6;
    gemm_body<FIN, FOUT, RELU_IN, A_BF16, OUT_FP8>(in_, Wbt, dinv, out, N, nwaves, wid, threadIdx.x & 63);
}

// ---------------- fp8 gather-aggregate: agg[n] = dinv[n]*(hs[n] + sum_e hs[src]) + b ----------------
// hs is fp8 e4m3 row-major [N][F]; lane covers 16 cols (16 B load); x4 edge unroll.
// Output bf16 row-major (next GEMM's A input).
template<int F>
__global__ __launch_bounds__(256) void agg8_kernel(const int* __restrict__ rowptr,
                                                   const int* __restrict__ csr_src,
                                                   const unsigned char* __restrict__ hs,
                                                   const float* __restrict__ dinv,
                                                   const float* __restrict__ b,
                                                   unsigned short* __restrict__ aggout, int N) {
    constexpr int TPN = F / 16;          // lanes per node (16 fp8 = 16 B each)
    constexpr int NPB = 256 / TPN;
    const int n = blockIdx.x * NPB + threadIdx.x / TPN;
    const int c16 = (threadIdx.x % TPN) * 16;
    if (n >= N) return;
    const uint4_* hp = (const uint4_*)hs;            // row = F/16 uint4
    const int lanep = c16 / 16;
    const int rstride = F / 16;
    int row = rowptr[n], end = rowptr[n + 1];
    float acc[16];
    {
        uint4_ u = hp[(size_t)n * rstride + lanep];   // self term
#pragma unroll
        for (int w = 0; w < 4; ++w) {
            f32x2 lo = __builtin_amdgcn_cvt_pk_f32_fp8(u[w], false);
            f32x2 hi = __builtin_amdgcn_cvt_pk_f32_fp8(u[w], true);
            acc[w * 4 + 0] = lo[0]; acc[w * 4 + 1] = lo[1];
            acc[w * 4 + 2] = hi[0]; acc[w * 4 + 3] = hi[1];
        }
    }
    int j = row;
    for (; j + 4 <= end; j += 4) {
        int s0 = csr_src[j], s1 = csr_src[j + 1], s2 = csr_src[j + 2], s3 = csr_src[j + 3];
        uint4_ u0 = hp[(size_t)s0 * rstride + lanep];
        uint4_ u1 = hp[(size_t)s1 * rstride + lanep];
        uint4_ u2 = hp[(size_t)s2 * rstride + lanep];
        uint4_ u3 = hp[(size_t)s3 * rstride + lanep];
#pragma unroll
        for (int w = 0; w < 4; ++w) {
            f32x2 a0 = __builtin_amdgcn_cvt_pk_f32_fp8(u0[w], false);
            f32x2 b0 = __builtin_amdgcn_cvt_pk_f32_fp8(u0[w], true);
            f32x2 a1 = __builtin_amdgcn_cvt_pk_f32_fp8(u1[w], false);
            f32x2 b1 = __builtin_amdgcn_cvt_pk_f32_fp8(u1[w], true);
            f32x2 a2 = __builtin_amdgcn_cvt_pk_f32_fp8(u2[w], false);
            f32x2 b2 = __builtin_amdgcn_cvt_pk_f32_fp8(u2[w], true);
            f32x2 a3 = __builtin_amdgcn_cvt_pk_f32_fp8(u3[w], false);
            f32x2 b3 = __builtin_amdgcn_cvt_pk_f32_fp8(u3[w], true);
            acc[w * 4 + 0] += (a0[0] + a1[0]) + (a2[0] + a3[0]);
            acc[w * 4 + 1] += (a0[1] + a1[1]) + (a2[1] + a3[1]);
            acc[w * 4 + 2] += (b0[0] + b1[0]) + (b2[0] + b3[0]);
            acc[w * 4 + 3] += (b0[1] + b1[1]) + (b2[1] + b3[1]);
        }
    }
    for (; j < end; ++j) {
        uint4_ u = hp[(size_t)csr_src[j] * rstride + lanep];
#pragma unroll
        for (int w = 0; w < 4; ++w) {
            f32x2 lo = __builtin_amdgcn_cvt_pk_f32_fp8(u[w], false);
            f32x2 hi = __builtin_amdgcn_cvt_pk_f32_fp8(u[w], true);
            acc[w * 4 + 0] += lo[0]; acc[w * 4 + 1] += lo[1];
            acc[w * 4 + 2] += hi[0]; acc[w * 4 + 3] += hi[1];
        }
    }
    float c = dinv[n];
    short8 o0, o1;
#pragma unroll
    for (int k = 0; k < 8; ++k) {
        o0[k] = (short)f2bf(fmaf(acc[k], c, b[c16 + k]));
        o1[k] = (short)f2bf(fmaf(acc[k + 8], c, b[c16 + 8 + k]));
    }
    unsigned short* op = aggout + (size_t)n * F + c16;
    *(short8*)op = o0;
    *(short8*)(op + 8) = o1;
}

// ---------------- layer-3: gather-agg (agg3 layout) + segmented LDS pool-reduce ----------------
// 64 contiguous nodes/block, 4 lanes/node (agg3's proven-dense layout). batch sorted ->
// block spans <=3 graphs; 32 walker threads flush one atomicAdd per (segment, col).
__global__ __launch_bounds__(256) void agg3pool_kernel(const int* __restrict__ rowptr,
                                                       const int* __restrict__ csr_src,
                                                       const unsigned short* __restrict__ hs,
                                                       const float* __restrict__ dinv,
                                                       const float* __restrict__ b,
                                                       const int* __restrict__ batch,
                                                       float* __restrict__ sums, int N) {
    constexpr int F = 32;
    __shared__ float sm[64][33];
    __shared__ int gid[64];
    const int t = threadIdx.x;
    const int slot = t >> 2;
    const int c8 = (t & 3) * 8;
    const int n = blockIdx.x * 64 + slot;
    if (t < 64) {
        int nn = blockIdx.x * 64 + t;
        gid[t] = (nn < N) ? batch[nn] : -1;
    }
    float acc[8];
    if (n < N) {
        int row = rowptr[n], end = rowptr[n + 1];
        {
            short8 h = *(const short8*)(hs + (size_t)n * F + c8);   // self term
#pragma unroll
            for (int k = 0; k < 8; ++k) acc[k] = bf2f((unsigned short)h[k]);
        }
        int j = row;
        for (; j + 4 <= end; j += 4) {
            int s0 = csr_src[j], s1 = csr_src[j + 1], s2 = csr_src[j + 2], s3 = csr_src[j + 3];
            short8 h0 = *(const short8*)(hs + (size_t)s0 * F + c8);
            short8 h1 = *(const short8*)(hs + (size_t)s1 * F + c8);
            short8 h2 = *(const short8*)(hs + (size_t)s2 * F + c8);
            short8 h3 = *(const short8*)(hs + (size_t)s3 * F + c8);
#pragma unroll
            for (int k = 0; k < 8; ++k)
                acc[k] += (bf2f((unsigned short)h0[k]) + bf2f((unsigned short)h1[k])) +
                          (bf2f((unsigned short)h2[k]) + bf2f((unsigned short)h3[k]));
        }
        for (; j < end; ++j) {
            short8 h = *(const short8*)(hs + (size_t)csr_src[j] * F + c8);
#pragma unroll
            for (int k = 0; k < 8; ++k) acc[k] += bf2f((unsigned short)h[k]);
        }
        float c = dinv[n];
#pragma unroll
        for (int k = 0; k < 8; ++k) acc[k] = fmaf(acc[k], c, b[c8 + k]);
    } else {
#pragma unroll
        for (int k = 0; k < 8; ++k) acc[k] = 0.f;
    }
#pragma unroll
    for (int k = 0; k < 8; ++k) sm[slot][c8 + k] = acc[k];
    __syncthreads();
    if (t < 32) {                                     // segmented flush, one col per thread
        int cur = -1; float run = 0.f;
        for (int s2 = 0; s2 < 64; ++s2) {
            int g = gid[s2];
            if (g < 0) break;                         // only trailing slots invalid
            float v = sm[s2][t];
            if (g != cur) {
                if (cur >= 0) atomicAdd(&sums[(size_t)cur * 32 + t], run);
                cur = g; run = v;
            } else {
                run += v;
            }
        }
        if (cur >= 0) atomicAdd(&sums[(size_t)cur * 32 + t], run);
    }
}

// ---------------- epilogue: divide by count, logits, sigmoid, BCE mean ----------------
__global__ __launch_bounds__(256) void final_kernel(const float* __restrict__ sums,
                                                    const int* __restrict__ gstart,
                                                    const float* __restrict__ Wl,
                                                    const float* __restrict__ bl,
                                                    const int* __restrict__ targets,
                                                    float* __restrict__ out) {
    __shared__ float red[256];
    float lsum = 0.0f;
    for (int g = threadIdx.x; g < NG; g += 256) {
        float c = fmaxf((float)(gstart[g + 1] - gstart[g]), 1.0f);
        float acc = bl[0];
#pragma unroll
        for (int k = 0; k < 32; ++k)
            acc = fmaf(sums[(size_t)g * 32 + k] / c, Wl[k], acc);
        out[g] = 1.0f / (1.0f + expf(-acc));
        float y = (float)targets[g];
        lsum += fmaxf(acc, 0.0f) - acc * y + log1pf(expf(-fabsf(acc)));
    }
    red[threadIdx.x] = lsum;
    __syncthreads();
    for (int s = 128; s > 0; s >>= 1) {
        if (threadIdx.x < s) red[threadIdx.x] += red[threadIdx.x + s];
        __syncthreads();
    }
    if (threadIdx.x == 0) out[NG] = red[0] / (float)NG;
}

extern "C" void kernel_launch(void* const* d_in, const int* in_sizes, int n_in,
                              void* d_out, int out_size, void* d_ws, size_t ws_size,
                              hipStream_t stream) {
    const float* x       = (const float*)d_in[0];
    const int*   ei      = (const int*)d_in[1];
    const int*   batch   = (const int*)d_in[2];
    const int*   targets = (const int*)d_in[3];
    const float* W1 = (const float*)d_in[4];
    const float* b1 = (const float*)d_in[5];
    const float* W2 = (const float*)d_in[6];
    const float* b2 = (const float*)d_in[7];
    const float* W3 = (const float*)d_in[8];
    const float* b3 = (const float*)d_in[9];
    const float* Wl = (const float*)d_in[10];
    const float* bl = (const float*)d_in[11];
    float* out = (float*)d_out;
    char*  ws  = (char*)d_ws;

    const int* src = ei;
    const int* dst = ei + NE;

    // workspace layout (byte offsets, 512B aligned) — total ~68.3 MB
    float*          dinv    = (float*)(ws);                    //    400,384 B
    int*            rowptr  = (int*)(ws + 400384);             //    400,384 B (NN+1)
    int*            csr_src = (int*)(ws + 800768);             //  6,400,512 B
    unsigned short* Wb1t    = (unsigned short*)(ws + 7201280); //     32,768 B (transposed)
    unsigned short* Wb2t    = (unsigned short*)(ws + 7234048); //     16,384 B (transposed)
    unsigned short* Wb3t    = (unsigned short*)(ws + 7250432); //      4,096 B (transposed)
    int*            gstart  = (int*)(ws + 7254528);            //      8,704 B (NG+1)
    unsigned char*  hsbuf   = (unsigned char*)(ws + 7263232);  // 25,600,512 B (fp8 / bf16 row-major)
    unsigned short* aggbuf  = (unsigned short*)(ws + 32863744);// 25,600,512 B (bf16 row-major)
    float*          sums    = (float*)(ws + 58464256);         //    262,144 B (pooled sums)
    int*            bdata   = (int*)(ws + 58726400);           //  9,609,216 B (391*6144*4)
    int*            gcnt    = (int*)(ws + 68335616);           //      2,048 B

    // ---- setup (w2bf + grange + gcnt zero + sums zero) ----
    setup_kernel<<<370, 256, 0, stream>>>(W1, W2, W3, Wb1t, Wb2t, Wb3t, batch, gstart, gcnt, sums);

    // ---- CSR build ----
    bin_kernel<<<(NE + CHUNK - 1) / CHUNK, 256, 0, stream>>>(src, dst, gcnt, bdata, NE);
    csr2a_kernel<<<NBUK, 256, 0, stream>>>(gcnt, bdata, dinv, rowptr);

    // ---- layer 1: CSR scatter || gemm1 (fused); then agg1 ----
    fill_gemm1_kernel<<<FILLB + GEMMB, 256, 0, stream>>>(gcnt, bdata, rowptr, csr_src,
                                                         x, Wb1t, dinv, hsbuf);
    agg8_kernel<128><<<(NN + 31) / 32, 256, 0, stream>>>(rowptr, csr_src, hsbuf, dinv, b1, aggbuf, NN);

    // ---- layer 2 ----
    mfma_gemm<128, 64, true, true, true><<<GEMMB, 256, 0, stream>>>(aggbuf, Wb2t, dinv, hsbuf, NN, GEMMB * 4);
    agg8_kernel<64><<<(NN + 63) / 64, 256, 0, stream>>>(rowptr, csr_src, hsbuf, dinv, b2, aggbuf, NN);

    // ---- layer 3: gemm (bf16 row-major out); agg+segmented-pool; epilogue ----
    mfma_gemm<64, 32, true, true, false><<<GEMMB, 256, 0, stream>>>(aggbuf, Wb3t, dinv, hsbuf, NN, GEMMB * 4);
    agg3pool_kernel<<<(NN + 63) / 64, 256, 0, stream>>>(rowptr, csr_src, (const unsigned short*)hsbuf,
                                                       dinv, b3, batch, sums, NN);
    final_kernel<<<1, 256, 0, stream>>>(sums, gstart, Wl, bl, targets, out);
}

// Round 15
// 297.320 us; speedup vs baseline: 1.1228x; 1.0219x over previous
//
#include <hip/hip_runtime.h>
#include <math.h>

#define NN 100000
#define NE 1600000
#define NG 2048
#define NBUK 391     // ceil(NN/256) dst-buckets, bucket = dst >> 8
#define SLOT 6144    // per-bucket capacity: mean 4096 + 32 sigma
#define CHUNK 8192   // edges per bin block
#define FILLB 391    // fill-path blocks in fused kernel
#define GEMMB 832    // gemm blocks (3328 waves, ~1.9 m-tiles/wave)

typedef __attribute__((ext_vector_type(8))) short short8;
typedef __attribute__((ext_vector_type(8))) __bf16 bf16x8;
typedef __attribute__((ext_vector_type(4))) float f32x4;
typedef __attribute__((ext_vector_type(2))) float f32x2;
typedef __attribute__((ext_vector_type(4))) unsigned int uint4_;

__device__ __forceinline__ unsigned short f2bf(float f) {       // RNE, finite inputs
    unsigned int u = __float_as_uint(f);
    return (unsigned short)((u + 0x7FFFu + ((u >> 16) & 1u)) >> 16);
}
__device__ __forceinline__ float bf2f(unsigned short s) {
    return __uint_as_float(((unsigned int)s) << 16);
}
__device__ __forceinline__ unsigned char f2fp8(float v) {       // HW cvt, e4m3fn
    int p = __builtin_amdgcn_cvt_pk_fp8_f32(v, v, 0, false);
    return (unsigned char)(p & 0xFF);
}

// ---------------- setup: w2bf (transposed) + grange + gcnt zero ----------------
__global__ __launch_bounds__(256) void setup_kernel(const float* __restrict__ W1,
                                                    const float* __restrict__ W2,
                                                    const float* __restrict__ W3,
                                                    unsigned short* __restrict__ Wb1t,
                                                    unsigned short* __restrict__ Wb2t,
                                                    unsigned short* __restrict__ Wb3t,
                                                    const int* __restrict__ batch,
                                                    int* __restrict__ gstart,
                                                    int* __restrict__ gcnt) {
    const int bid = blockIdx.x, t = threadIdx.x;
    if (bid < 104) {                                  // weight cvt+transpose (26624 elems)
        int i = bid * 256 + t;
        if (i < 16384) {                              // W1: 128x128
            int k = i >> 7, c = i & 127;
            Wb1t[c * 128 + k] = f2bf(W1[i]);
        } else if (i < 24576) {                       // W2: 128x64
            int j = i - 16384; int k = j >> 6, c = j & 63;
            Wb2t[c * 128 + k] = f2bf(W2[j]);
        } else if (i < 26624) {                       // W3: 64x32
            int j = i - 24576; int k = j >> 5, c = j & 31;
            Wb3t[c * 64 + k] = f2bf(W3[j]);
        }
    } else if (bid < 113) {                           // grange (batch sorted)
        int g = (bid - 104) * 256 + t;
        if (g > NG) return;
        if (g == NG) { gstart[g] = NN; return; }
        int lo = 0, hi = NN;
        while (lo < hi) { int mid = (lo + hi) >> 1; if (batch[mid] < g) lo = mid + 1; else hi = mid; }
        gstart[g] = lo;
    } else {                                          // zero gcnt (512 ints)
        gcnt[t] = 0; gcnt[t + 256] = 0;
    }
}

// ---------------- pass 1: bin edges by dst>>8, bucket-sorted block appends ----------------
__global__ __launch_bounds__(256) void bin_kernel(const int* __restrict__ src,
                                                  const int* __restrict__ dst,
                                                  int* __restrict__ gcnt,
                                                  int* __restrict__ bucket_data, int E) {
    __shared__ int cnt[512];                 // padded scan array
    __shared__ int offs[NBUK];
    __shared__ int cnt2[NBUK];
    __shared__ int gb[NBUK];
    __shared__ int packB[CHUNK];
    __shared__ unsigned short bktB[CHUNK];
    const int t = threadIdx.x;
    const int E0 = blockIdx.x * CHUNK;
    const int valid = min(CHUNK, E - E0);
    cnt[t] = 0; cnt[t + 256] = 0;
    for (int i = t; i < NBUK; i += 256) cnt2[i] = 0;
    __syncthreads();
    // A: count buckets
    for (int i = t; i < valid; i += 256)
        atomicAdd(&cnt[dst[E0 + i] >> 8], 1);
    __syncthreads();
    int o0 = cnt[t], o1 = cnt[t + 256];
    // B: inclusive Hillis-Steele scan over 512 (2 elems/thread)
    for (int off = 1; off < 512; off <<= 1) {
        int a0 = (t >= off) ? cnt[t - off] : 0;
        int a1 = (t + 256 >= off) ? cnt[t + 256 - off] : 0;
        __syncthreads();
        cnt[t] += a0; cnt[t + 256] += a1;
        __syncthreads();
    }
    if (t < NBUK)       { offs[t] = cnt[t] - o0;             gb[t] = o0 ? atomicAdd(&gcnt[t], o0) : 0; }
    if (t + 256 < NBUK) { offs[t + 256] = cnt[t + 256] - o1; gb[t + 256] = o1 ? atomicAdd(&gcnt[t + 256], o1) : 0; }
    __syncthreads();
    // C: re-read edges, place bucket-sorted into LDS
    for (int i = t; i < valid; i += 256) {
        int s = src[E0 + i], d = dst[E0 + i];
        int b = d >> 8;
        int pos = offs[b] + atomicAdd(&cnt2[b], 1);
        packB[pos] = (s << 8) | (d & 255);
        bktB[pos] = (unsigned short)b;
    }
    __syncthreads();
    // D: contiguous-per-bucket append to global streams
    for (int i = t; i < valid; i += 256) {
        int b = bktB[i];
        int idx = gb[b] + (i - offs[b]);
        if (idx < SLOT) bucket_data[b * SLOT + idx] = packB[i];
    }
}

// ---------------- pass 2a: per-bucket counts -> dinv + rowptr (base scanned inline) ----------------
__global__ __launch_bounds__(256) void csr2a_kernel(const int* __restrict__ gcnt,
                                                    const int* __restrict__ bucket_data,
                                                    float* __restrict__ dinv,
                                                    int* __restrict__ rowptr) {
    __shared__ int bs[512];
    __shared__ int counts[256];
    __shared__ int base_sh;
    const int t = threadIdx.x;
    const int b = blockIdx.x;
    // inline exclusive scan of min(gcnt,SLOT) over all buckets (redundant per block)
    bs[t] = (t < NBUK) ? min(gcnt[t], SLOT) : 0;
    bs[t + 256] = (t + 256 < NBUK) ? min(gcnt[t + 256], SLOT) : 0;
    counts[t] = 0;
    __syncthreads();
    for (int off = 1; off < 512; off <<= 1) {
        int a0 = (t >= off) ? bs[t - off] : 0;
        int a1 = (t + 256 >= off) ? bs[t + 256 - off] : 0;
        __syncthreads();
        bs[t] += a0; bs[t + 256] += a1;
        __syncthreads();
    }
    if (t == 0) base_sh = bs[b] - min(gcnt[b], SLOT);   // exclusive base
    __syncthreads();
    const int cb = min(gcnt[b], SLOT);
    const int* bd = bucket_data + b * SLOT;
    for (int i = t; i < cb; i += 256) atomicAdd(&counts[bd[i] & 255], 1);
    __syncthreads();
    int c = counts[t];
    for (int off = 1; off < 256; off <<= 1) {
        int a = (t >= off) ? counts[t - off] : 0;
        __syncthreads();
        counts[t] += a;
        __syncthreads();
    }
    int excl = counts[t] - c;
    int node = b * 256 + t;
    if (node < NN) {
        dinv[node] = rsqrtf((float)c + 1.0f);
        rowptr[node] = base_sh + excl;
    }
    if (b == NBUK - 1 && t == 0) rowptr[NN] = NE;
}

// ---------------- MFMA GEMM body ----------------
// One wave per 16-row m-tile computing ALL FOUT cols; grid-stride with register
// double-buffer: next A-tile loads issue BEFORE current tile's MFMA block.
// OUT_FP8: hs written ROW-MAJOR fp8 (chunk-major regressed — R12: divergence cost
// beat the FETCH win; gather is issue-bound at ~2 TB/s, not BW-bound).
// Layouts [m89-verified]: A: m=lane&15, k=quad*8+j ; B: n=lane&15, k=quad*8+j ;
//                         C/D: col=lane&15, row=quad*4+reg.
template<int FIN, int FOUT, bool RELU_IN, bool A_BF16, bool OUT_FP8>
__device__ __forceinline__ void gemm_body(const void* __restrict__ in_,
                                          const unsigned short* __restrict__ Wbt,
                                          const float* __restrict__ dinv,
                                          void* __restrict__ out,
                                          int N, int nwaves, int wid, int lane) {
    constexpr int NT = FOUT / 16;
    constexpr int KS = FIN / 32;
    const int m16  = lane & 15;
    const int quad = lane >> 4;
    const int koff = quad * 8;

    short8 bfrag[NT][KS];
#pragma unroll
    for (int nt = 0; nt < NT; ++nt) {
        const unsigned short* wcol = Wbt + (size_t)(m16 + nt * 16) * FIN + koff;
#pragma unroll
        for (int ks = 0; ks < KS; ++ks)
            bfrag[nt][ks] = *(const short8*)(wcol + ks * 32);
    }

    const int MT = N / 16;                 // N == 100000 -> exact
    int mt = wid;
    if (mt >= MT) return;

    short8 curB[KS], nxtB[KS];
    f32x4  curF[KS][2], nxtF[KS][2];

    auto load_raw = [&](int m, short8* rb, f32x4 (*rf)[2]) {
        const int row = m * 16 + m16;
        if (A_BF16) {
            const unsigned short* A = (const unsigned short*)in_ + (size_t)row * FIN + koff;
#pragma unroll
            for (int ks = 0; ks < KS; ++ks) rb[ks] = *(const short8*)(A + ks * 32);
        } else {
            const float* A = (const float*)in_ + (size_t)row * FIN + koff;
#pragma unroll
            for (int ks = 0; ks < KS; ++ks) {
                rf[ks][0] = *(const f32x4*)(A + ks * 32);
                rf[ks][1] = *(const f32x4*)(A + ks * 32 + 4);
            }
        }
    };

    load_raw(mt, curB, curF);
    while (true) {
        const int mtn = mt + nwaves;
        const bool have_next = (mtn < MT);
        if (have_next) load_raw(mtn, nxtB, nxtF);   // in flight across the MFMAs below

        short8 afrag[KS];
        if (A_BF16) {
#pragma unroll
            for (int ks = 0; ks < KS; ++ks) {
                short8 a = curB[ks];
                if (RELU_IN) {
#pragma unroll
                    for (int j = 0; j < 8; ++j)
                        a[j] = (short)(((unsigned short)a[j] & 0x8000u) ? 0 : (unsigned short)a[j]);
                }
                afrag[ks] = a;
            }
        } else {
#pragma unroll
            for (int ks = 0; ks < KS; ++ks) {
#pragma unroll
                for (int j = 0; j < 4; ++j) {
                    float a0 = curF[ks][0][j], a1 = curF[ks][1][j];
                    if (RELU_IN) { a0 = fmaxf(a0, 0.f); a1 = fmaxf(a1, 0.f); }
                    afrag[ks][j]     = (short)f2bf(a0);
                    afrag[ks][j + 4] = (short)f2bf(a1);
                }
            }
        }

        f32x4 acc[NT];
#pragma unroll
        for (int nt = 0; nt < NT; ++nt) acc[nt] = (f32x4){0.f, 0.f, 0.f, 0.f};
#pragma unroll
        for (int nt = 0; nt < NT; ++nt)
#pragma unroll
            for (int ks = 0; ks < KS; ++ks)
                acc[nt] = __builtin_amdgcn_mfma_f32_16x16x32_bf16(
                    __builtin_bit_cast(bf16x8, afrag[ks]),
                    __builtin_bit_cast(bf16x8, bfrag[nt][ks]), acc[nt], 0, 0, 0);

        float dv[4];
#pragma unroll
        for (int r = 0; r < 4; ++r) dv[r] = dinv[mt * 16 + quad * 4 + r];
#pragma unroll
        for (int nt = 0; nt < NT; ++nt) {
            const int col = m16 + nt * 16;
#pragma unroll
            for (int r = 0; r < 4; ++r) {
                int orow = mt * 16 + quad * 4 + r;
                float v = acc[nt][r] * dv[r];
                if (OUT_FP8)
                    ((unsigned char*)out)[(size_t)orow * FOUT + col] = f2fp8(v);
                else
                    ((unsigned short*)out)[(size_t)orow * FOUT + col] = f2bf(v);
            }
        }

        if (!have_next) break;
#pragma unroll
        for (int ks = 0; ks < KS; ++ks) {
            curB[ks] = nxtB[ks];
            curF[ks][0] = nxtF[ks][0];
            curF[ks][1] = nxtF[ks][1];
        }
        mt = mtn;
    }
}

// ---------------- fused: CSR fine-scatter (blocks 0..390) || gemm1 (rest) ----------------
__global__ __launch_bounds__(256, 2) void fill_gemm1_kernel(const int* __restrict__ gcnt,
                                                            const int* __restrict__ bucket_data,
                                                            const int* __restrict__ rowptr,
                                                            int* __restrict__ csr_src,
                                                            const float* __restrict__ x,
                                                            const unsigned short* __restrict__ Wb1t,
                                                            const float* __restrict__ dinv,
                                                            unsigned char* __restrict__ hs) {
    __shared__ int offs[256];
    __shared__ int cnt2[256];
    const int t = threadIdx.x;
    if (blockIdx.x < FILLB) {
        const int b = blockIdx.x;
        const int cb = min(gcnt[b], SLOT);
        const int* bd = bucket_data + b * SLOT;
        int node = b * 256 + t;
        offs[t] = (node < NN) ? rowptr[node] : 0;
        cnt2[t] = 0;
        __syncthreads();
        for (int i = t; i < cb; i += 256) {
            int p = bd[i];
            int local = p & 255;
            int pos = atomicAdd(&cnt2[local], 1);
            csr_src[offs[local] + pos] = p >> 8;   // p>=0, arith shift ok
        }
    } else {
        const int wid = ((blockIdx.x - FILLB) * 256 + t) >> 6;
        gemm_body<128, 128, false, false, true>(x, Wb1t, dinv, hs, NN, GEMMB * 4, wid, t & 63);
    }
}

// ---------------- standalone GEMMs (layers 2,3) ----------------
template<int FIN, int FOUT, bool RELU_IN, bool A_BF16, bool OUT_FP8>
__global__ __launch_bounds__(256, 2) void mfma_gemm(const void* __restrict__ in_,
                                                    const unsigned short* __restrict__ Wbt,
                                                    const float* __restrict__ dinv,
                                                    void* __restrict__ out,
                                                    int N, int nwaves) {
    const int wid = (blockIdx.x * 256 + threadIdx.x) >> 6;
    gemm_body<FIN, FOUT, RELU_IN, A_BF16, OUT_FP8>(in_, Wbt, dinv, out, N, nwaves, wid, threadIdx.x & 63);
}

// ---------------- fp8 gather-aggregate: agg[n] = dinv[n]*(hs[n] + sum_e hs[src]) + b ----------------
// hs is fp8 e4m3 row-major [N][F]; lane covers 16 cols (16 B load); x4 edge unroll.
// Output bf16 row-major (next GEMM's A input).
template<int F>
__global__ __launch_bounds__(256) void agg8_kernel(const int* __restrict__ rowptr,
                                                   const int* __restrict__ csr_src,
                                                   const unsigned char* __restrict__ hs,
                                                   const float* __restrict__ dinv,
                                                   const float* __restrict__ b,
                                                   unsigned short* __restrict__ aggout, int N) {
    constexpr int TPN = F / 16;          // lanes per node (16 fp8 = 16 B each)
    constexpr int NPB = 256 / TPN;
    const int n = blockIdx.x * NPB + threadIdx.x / TPN;
    const int c16 = (threadIdx.x % TPN) * 16;
    if (n >= N) return;
    const uint4_* hp = (const uint4_*)hs;            // row = F/16 uint4
    const int lanep = c16 / 16;
    const int rstride = F / 16;
    int row = rowptr[n], end = rowptr[n + 1];
    float acc[16];
    {
        uint4_ u = hp[(size_t)n * rstride + lanep];   // self term
#pragma unroll
        for (int w = 0; w < 4; ++w) {
            f32x2 lo = __builtin_amdgcn_cvt_pk_f32_fp8(u[w], false);
            f32x2 hi = __builtin_amdgcn_cvt_pk_f32_fp8(u[w], true);
            acc[w * 4 + 0] = lo[0]; acc[w * 4 + 1] = lo[1];
            acc[w * 4 + 2] = hi[0]; acc[w * 4 + 3] = hi[1];
        }
    }
    int j = row;
    for (; j + 4 <= end; j += 4) {
        int s0 = csr_src[j], s1 = csr_src[j + 1], s2 = csr_src[j + 2], s3 = csr_src[j + 3];
        uint4_ u0 = hp[(size_t)s0 * rstride + lanep];
        uint4_ u1 = hp[(size_t)s1 * rstride + lanep];
        uint4_ u2 = hp[(size_t)s2 * rstride + lanep];
        uint4_ u3 = hp[(size_t)s3 * rstride + lanep];
#pragma unroll
        for (int w = 0; w < 4; ++w) {
            f32x2 a0 = __builtin_amdgcn_cvt_pk_f32_fp8(u0[w], false);
            f32x2 b0 = __builtin_amdgcn_cvt_pk_f32_fp8(u0[w], true);
            f32x2 a1 = __builtin_amdgcn_cvt_pk_f32_fp8(u1[w], false);
            f32x2 b1 = __builtin_amdgcn_cvt_pk_f32_fp8(u1[w], true);
            f32x2 a2 = __builtin_amdgcn_cvt_pk_f32_fp8(u2[w], false);
            f32x2 b2 = __builtin_amdgcn_cvt_pk_f32_fp8(u2[w], true);
            f32x2 a3 = __builtin_amdgcn_cvt_pk_f32_fp8(u3[w], false);
            f32x2 b3 = __builtin_amdgcn_cvt_pk_f32_fp8(u3[w], true);
            acc[w * 4 + 0] += (a0[0] + a1[0]) + (a2[0] + a3[0]);
            acc[w * 4 + 1] += (a0[1] + a1[1]) + (a2[1] + a3[1]);
            acc[w * 4 + 2] += (b0[0] + b1[0]) + (b2[0] + b3[0]);
            acc[w * 4 + 3] += (b0[1] + b1[1]) + (b2[1] + b3[1]);
        }
    }
    for (; j < end; ++j) {
        uint4_ u = hp[(size_t)csr_src[j] * rstride + lanep];
#pragma unroll
        for (int w = 0; w < 4; ++w) {
            f32x2 lo = __builtin_amdgcn_cvt_pk_f32_fp8(u[w], false);
            f32x2 hi = __builtin_amdgcn_cvt_pk_f32_fp8(u[w], true);
            acc[w * 4 + 0] += lo[0]; acc[w * 4 + 1] += lo[1];
            acc[w * 4 + 2] += hi[0]; acc[w * 4 + 3] += hi[1];
        }
    }
    float c = dinv[n];
    short8 o0, o1;
#pragma unroll
    for (int k = 0; k < 8; ++k) {
        o0[k] = (short)f2bf(fmaf(acc[k], c, b[c16 + k]));
        o1[k] = (short)f2bf(fmaf(acc[k + 8], c, b[c16 + 8 + k]));
    }
    unsigned short* op = aggout + (size_t)n * F + c16;
    *(short8*)op = o0;
    *(short8*)(op + 8) = o1;
}

// ---------------- bf16 gather-aggregate (layer 3): fp32 out for pooling ----------------
__global__ __launch_bounds__(256) void agg3_kernel(const int* __restrict__ rowptr,
                                                   const int* __restrict__ csr_src,
                                                   const unsigned short* __restrict__ hs,
                                                   const float* __restrict__ dinv,
                                                   const float* __restrict__ b,
                                                   float* __restrict__ aggout, int N) {
    constexpr int F = 32, TPN = 4, NPB = 64;
    int n = blockIdx.x * NPB + threadIdx.x / TPN;
    int c8 = (threadIdx.x % TPN) * 8;
    if (n >= N) return;
    int row = rowptr[n], end = rowptr[n + 1];
    float acc[8];
    {
        short8 h = *(const short8*)(hs + (size_t)n * F + c8);   // self term
#pragma unroll
        for (int j = 0; j < 8; ++j) acc[j] = bf2f((unsigned short)h[j]);
    }
    int j = row;
    for (; j + 4 <= end; j += 4) {
        int s0 = csr_src[j], s1 = csr_src[j + 1], s2 = csr_src[j + 2], s3 = csr_src[j + 3];
        short8 h0 = *(const short8*)(hs + (size_t)s0 * F + c8);
        short8 h1 = *(const short8*)(hs + (size_t)s1 * F + c8);
        short8 h2 = *(const short8*)(hs + (size_t)s2 * F + c8);
        short8 h3 = *(const short8*)(hs + (size_t)s3 * F + c8);
#pragma unroll
        for (int k = 0; k < 8; ++k)
            acc[k] += (bf2f((unsigned short)h0[k]) + bf2f((unsigned short)h1[k])) +
                      (bf2f((unsigned short)h2[k]) + bf2f((unsigned short)h3[k]));
    }
    for (; j < end; ++j) {
        int s = csr_src[j];
        short8 h = *(const short8*)(hs + (size_t)s * F + c8);
#pragma unroll
        for (int k = 0; k < 8; ++k) acc[k] += bf2f((unsigned short)h[k]);
    }
    float c = dinv[n];
    f32x4 o0, o1;
#pragma unroll
    for (int k = 0; k < 4; ++k) {
        o0[k] = fmaf(acc[k], c, b[c8 + k]);
        o1[k] = fmaf(acc[k + 4], c, b[c8 + k + 4]);
    }
    float* of = aggout + (size_t)n * F + c8;
    *(f32x4*)of = o0;
    *(f32x4*)(of + 4) = o1;
}

// ---------------- pool: pooled[g,:] = mean of h rows in [gstart[g], gstart[g+1]) ----------------
__global__ __launch_bounds__(256) void pool2_kernel(const float* __restrict__ h,
                                                    const int* __restrict__ gstart,
                                                    float* __restrict__ pooled) {
    __shared__ float sm[256];
    int g = blockIdx.x;
    int s = gstart[g], e = gstart[g + 1];
    int f = threadIdx.x & 31, slot = threadIdx.x >> 5;
    float acc = 0.f;
    for (int n = s + slot; n < e; n += 8) acc += h[(size_t)n * 32 + f];
    sm[threadIdx.x] = acc;
    __syncthreads();
    if (threadIdx.x < 128) sm[threadIdx.x] += sm[threadIdx.x + 128];
    __syncthreads();
    if (threadIdx.x < 64) sm[threadIdx.x] += sm[threadIdx.x + 64];
    __syncthreads();
    if (threadIdx.x < 32) {
        float v = sm[threadIdx.x] + sm[threadIdx.x + 32];
        float cntf = fmaxf((float)(e - s), 1.0f);
        pooled[(size_t)g * 32 + f] = v / cntf;
    }
}

// ---------------- epilogue: logits, sigmoid, BCE mean ----------------
__global__ __launch_bounds__(256) void final_kernel(const float* __restrict__ pooled,
                                                    const float* __restrict__ Wl,
                                                    const float* __restrict__ bl,
                                                    const int* __restrict__ targets,
                                                    float* __restrict__ out) {
    __shared__ float red[256];
    float lsum = 0.0f;
    for (int g = threadIdx.x; g < NG; g += 256) {
        float acc = bl[0];
#pragma unroll
        for (int k = 0; k < 32; ++k)
            acc = fmaf(pooled[(size_t)g * 32 + k], Wl[k], acc);
        out[g] = 1.0f / (1.0f + expf(-acc));
        float y = (float)targets[g];
        lsum += fmaxf(acc, 0.0f) - acc * y + log1pf(expf(-fabsf(acc)));
    }
    red[threadIdx.x] = lsum;
    __syncthreads();
    for (int s = 128; s > 0; s >>= 1) {
        if (threadIdx.x < s) red[threadIdx.x] += red[threadIdx.x + s];
        __syncthreads();
    }
    if (threadIdx.x == 0) out[NG] = red[0] / (float)NG;
}

extern "C" void kernel_launch(void* const* d_in, const int* in_sizes, int n_in,
                              void* d_out, int out_size, void* d_ws, size_t ws_size,
                              hipStream_t stream) {
    const float* x       = (const float*)d_in[0];
    const int*   ei      = (const int*)d_in[1];
    const int*   batch   = (const int*)d_in[2];
    const int*   targets = (const int*)d_in[3];
    const float* W1 = (const float*)d_in[4];
    const float* b1 = (const float*)d_in[5];
    const float* W2 = (const float*)d_in[6];
    const float* b2 = (const float*)d_in[7];
    const float* W3 = (const float*)d_in[8];
    const float* b3 = (const float*)d_in[9];
    const float* Wl = (const float*)d_in[10];
    const float* bl = (const float*)d_in[11];
    float* out = (float*)d_out;
    char*  ws  = (char*)d_ws;

    const int* src = ei;
    const int* dst = ei + NE;

    // workspace layout (byte offsets, 512B aligned) — total ~68.3 MB
    float*          dinv    = (float*)(ws);                    //    400,384 B
    int*            rowptr  = (int*)(ws + 400384);             //    400,384 B (NN+1)
    int*            csr_src = (int*)(ws + 800768);             //  6,400,512 B
    unsigned short* Wb1t    = (unsigned short*)(ws + 7201280); //     32,768 B (transposed)
    unsigned short* Wb2t    = (unsigned short*)(ws + 7234048); //     16,384 B (transposed)
    unsigned short* Wb3t    = (unsigned short*)(ws + 7250432); //      4,096 B (transposed)
    int*            gstart  = (int*)(ws + 7254528);            //      8,704 B (NG+1)
    unsigned char*  hsbuf   = (unsigned char*)(ws + 7263232);  // 25,600,512 B (fp8 / bf16 row-major)
    unsigned short* aggbuf  = (unsigned short*)(ws + 32863744);// 25,600,512 B (bf16/fp32 row-major)
    float*          pooled  = (float*)(ws + 58464256);         //    262,144 B
    int*            bdata   = (int*)(ws + 58726400);           //  9,609,216 B (391*6144*4)
    int*            gcnt    = (int*)(ws + 68335616);           //      2,048 B

    // ---- setup (w2bf + grange + gcnt zero) ----
    setup_kernel<<<114, 256, 0, stream>>>(W1, W2, W3, Wb1t, Wb2t, Wb3t, batch, gstart, gcnt);

    // ---- CSR build ----
    bin_kernel<<<(NE + CHUNK - 1) / CHUNK, 256, 0, stream>>>(src, dst, gcnt, bdata, NE);
    csr2a_kernel<<<NBUK, 256, 0, stream>>>(gcnt, bdata, dinv, rowptr);

    // ---- layer 1: CSR scatter || gemm1 (fused); then agg1 ----
    fill_gemm1_kernel<<<FILLB + GEMMB, 256, 0, stream>>>(gcnt, bdata, rowptr, csr_src,
                                                         x, Wb1t, dinv, hsbuf);
    agg8_kernel<128><<<(NN + 31) / 32, 256, 0, stream>>>(rowptr, csr_src, hsbuf, dinv, b1, aggbuf, NN);

    // ---- layer 2 ----
    mfma_gemm<128, 64, true, true, true><<<GEMMB, 256, 0, stream>>>(aggbuf, Wb2t, dinv, hsbuf, NN, GEMMB * 4);
    agg8_kernel<64><<<(NN + 63) / 64, 256, 0, stream>>>(rowptr, csr_src, hsbuf, dinv, b2, aggbuf, NN);

    // ---- layer 3: gemm (bf16 row-major out); agg fp32 out; pool ----
    mfma_gemm<64, 32, true, true, false><<<GEMMB, 256, 0, stream>>>(aggbuf, Wb3t, dinv, hsbuf, NN, GEMMB * 4);
    agg3_kernel<<<(NN + 63) / 64, 256, 0, stream>>>(rowptr, csr_src,
        (const unsigned short*)hsbuf, dinv, b3, (float*)aggbuf, NN);
    pool2_kernel<<<NG, 256, 0, stream>>>((const float*)aggbuf, gstart, pooled);

    // ---- epilogue ----
    final_kernel<<<1, 256, 0, stream>>>(pooled, Wl, bl, targets, out);
}